// Round 2
// baseline (534.582 us; speedup 1.0000x reference)
//
#include <hip/hip_runtime.h>
#include <hip/hip_bf16.h>

typedef __hip_bfloat16 bf16;

#define HID 128
#define PD  16
#define BB  4096
#define TT  262144
#define VD  10000
#define VP  4000
#define VA  4000
#define NGD 13000
#define NGP 5200
#define NGA 5200

__device__ __forceinline__ float b2f(bf16 x) { return __bfloat162float(x); }

union Pack4 { bf16 h[4]; uint2 u; };

// ---------------- K1: U[g,jj] = sum_k emb[g,k] * Bmat[k,jj]   (f32 in, bf16 out)
// Bmat[k,jj] = (jj<128) ? Wl[jj,k] : Wl[jj-128, 128+k]   (Wl row-major 128x256)
__global__ __launch_bounds__(256) void stage1_gemm(
    const float* __restrict__ emb, const float* __restrict__ Wl,
    bf16* __restrict__ U, int NG)
{
    __shared__ float Alds[32][33];
    __shared__ float Blds[32][260];
    const int tid  = threadIdx.x;
    const int row0 = blockIdx.x * 32;
    const int rbase = (tid >> 6) * 8;
    const int cbase = (tid & 63) * 4;
    float acc[8][4];
#pragma unroll
    for (int i = 0; i < 8; ++i)
#pragma unroll
        for (int j = 0; j < 4; ++j) acc[i][j] = 0.f;

    for (int k0 = 0; k0 < 128; k0 += 32) {
        {
            int i = tid;
#pragma unroll
            for (int it = 0; it < 4; ++it) {
                int r = i >> 5, kk = i & 31;
                int g = row0 + r;
                Alds[r][kk] = (g < NG) ? emb[(size_t)g * HID + k0 + kk] : 0.f;
                i += 256;
            }
        }
        {
            int i = tid;
#pragma unroll
            for (int it = 0; it < 32; ++it) {
                int kk = i & 31, jj = i >> 5;
                int k = k0 + kk;
                float v = (jj < 128) ? Wl[jj * 256 + k] : Wl[(jj - 128) * 256 + 128 + k];
                Blds[kk][jj] = v;
                i += 256;
            }
        }
        __syncthreads();
#pragma unroll
        for (int kk = 0; kk < 32; ++kk) {
            float bq[4];
#pragma unroll
            for (int j = 0; j < 4; ++j) bq[j] = Blds[kk][cbase + j];
#pragma unroll
            for (int i = 0; i < 8; ++i) {
                float a = Alds[rbase + i][kk];
#pragma unroll
                for (int j = 0; j < 4; ++j) acc[i][j] += a * bq[j];
            }
        }
        __syncthreads();
    }
#pragma unroll
    for (int i = 0; i < 8; ++i) {
        int g = row0 + rbase + i;
        if (g < NG) {
            Pack4 pk;
#pragma unroll
            for (int j = 0; j < 4; ++j) pk.h[j] = __float2bfloat16(acc[i][j]);
            *reinterpret_cast<uint2*>(&U[(size_t)g * 256 + cbase]) = pk.u;
        }
    }
}

// ---------------- K2: aw + softmax + accumulate global s_sum (per section)
template <int L>
__global__ __launch_bounds__(256) void aw_kernel(
    const bf16* __restrict__ U, const int* __restrict__ anc, const int* __restrict__ leaf,
    const float* __restrict__ bl, const float* __restrict__ ap,
    float* __restrict__ s_out, int V)
{
    __shared__ float sacc[L];
    const int tid = threadIdx.x;
    if (tid < L) sacc[tid] = 0.f;
    __syncthreads();
    const int lane = tid & 63;
    const int wid  = blockIdx.x * 4 + (tid >> 6);
    const int nw   = gridDim.x * 4;
    const float bl0 = bl[lane], bl1 = bl[lane + 64];
    const float ap0 = ap[lane], ap1 = ap[lane + 64];
    float wacc[L];
#pragma unroll
    for (int l = 0; l < L; ++l) wacc[l] = 0.f;

    for (int v = wid; v < V; v += nw) {
        float aw[L];
#pragma unroll
        for (int l = 0; l < L; ++l) {
            int a = anc[v * L + l];
            int f = leaf[v * L + l];
            const bf16* Ua = U + (size_t)a * 256;
            const bf16* Ul = U + (size_t)f * 256 + 128;
            float t0 = tanhf(b2f(Ua[lane]) + b2f(Ul[lane]) + bl0);
            float t1 = tanhf(b2f(Ua[lane + 64]) + b2f(Ul[lane + 64]) + bl1);
            float p = t0 * ap0 + t1 * ap1;
#pragma unroll
            for (int off = 32; off; off >>= 1) p += __shfl_xor(p, off, 64);
            aw[l] = p;
        }
        float m = aw[0];
#pragma unroll
        for (int l = 1; l < L; ++l) m = fmaxf(m, aw[l]);
        float den = 0.f, e[L];
#pragma unroll
        for (int l = 0; l < L; ++l) { e[l] = __expf(aw[l] - m); den += e[l]; }
        float inv = 1.f / den;
#pragma unroll
        for (int l = 0; l < L; ++l) wacc[l] += e[l] * inv;
    }
    if (lane == 0) {
#pragma unroll
        for (int l = 0; l < L; ++l) atomicAdd(&sacc[l], wacc[l]);
    }
    __syncthreads();
    if (tid < L) atomicAdd(&s_out[tid], sacc[tid]);
}

// ---------------- K3: all_emb[v,:] = sum_l s[l] * emb[anc[v,l],:]   (f32)
template <int L>
__global__ __launch_bounds__(256) void allemb_kernel(
    const float* __restrict__ emb, const int* __restrict__ anc,
    const float* __restrict__ s, float* __restrict__ out, int V)
{
    const int tid  = threadIdx.x;
    const int lane = tid & 63;
    const int wid  = blockIdx.x * 4 + (tid >> 6);
    const int nw   = gridDim.x * 4;
    float sv[L];
#pragma unroll
    for (int l = 0; l < L; ++l) sv[l] = s[l];
    for (int v = wid; v < V; v += nw) {
        float a0 = 0.f, a1 = 0.f;
#pragma unroll
        for (int l = 0; l < L; ++l) {
            const float* e = emb + (size_t)anc[v * L + l] * HID;
            a0 += sv[l] * e[lane];
            a1 += sv[l] * e[lane + 64];
        }
        out[(size_t)v * HID + lane]      = a0;
        out[(size_t)v * HID + lane + 64] = a1;
    }
}

// ---------------- K4: segment sum over sorted batch ids (one block per segment b)
__global__ __launch_bounds__(128) void segsum_kernel(
    const float* __restrict__ all_emb, const int* __restrict__ x,
    const int* __restrict__ batch, float* __restrict__ out)
{
    const int b   = blockIdx.x;
    const int tid = threadIdx.x;
    int l = 0, r = TT;
    while (l < r) { int m = (l + r) >> 1; if (batch[m] < b) l = m + 1; else r = m; }
    const int lo = l;
    r = TT;
    while (l < r) { int m = (l + r) >> 1; if (batch[m] < b + 1) l = m + 1; else r = m; }
    const int hi = l;
    float acc = 0.f;
    int t = lo;
    for (; t + 3 < hi; t += 4) {
        int i0 = x[t], i1 = x[t + 1], i2 = x[t + 2], i3 = x[t + 3];
        acc += all_emb[(size_t)i0 * HID + tid];
        acc += all_emb[(size_t)i1 * HID + tid];
        acc += all_emb[(size_t)i2 * HID + tid];
        acc += all_emb[(size_t)i3 * HID + tid];
    }
    for (; t < hi; ++t) acc += all_emb[(size_t)x[t] * HID + tid];
    out[(size_t)b * HID + tid] = acc;
}

// ---------------- K5: fused NTN GEMM + epilogue.
// Block = 256 thr, 16 rows (b). For each of 8 col-chunks (256 cols = 16 j x 16 p):
// GEMM C[b, j*16+p] = sum_k le[b,k]*W2[k, j*16+p], immediately contracted with re.
// Then block term, tanh, fc, sigmoid.
__global__ __launch_bounds__(256) void ntn_fused(
    const float* __restrict__ le, const float* __restrict__ re,
    const float* __restrict__ W2,   // 128 x 2048  (= W_ntn flat)
    const float* __restrict__ Vntn, // 16 x 256
    const float* __restrict__ bntn, const float* __restrict__ wfc,
    const float* __restrict__ bfc, float* __restrict__ out)
{
    __shared__ float Alds[16][132];
    __shared__ float Rlds[16][132];
    __shared__ float Blds[32][260];
    const int tid   = threadIdx.x;
    const int row0  = blockIdx.x * 16;
    const int rbase = (tid >> 6) * 4;   // 4 rows per wave
    const int lane  = tid & 63;
    const int cbase = lane * 4;         // col within chunk [0,256)
    const int jloc  = lane >> 2;        // j within chunk [0,16)
    const int pq    = (lane & 3) * 4;   // p base, this lane owns p = pq..pq+3

    for (int i = tid; i < 16 * 128; i += 256) {
        int r = i >> 7, c = i & 127;
        Alds[r][c] = le[(size_t)(row0 + r) * HID + c];
        Rlds[r][c] = re[(size_t)(row0 + r) * HID + c];
    }
    __syncthreads();

    float blin[4][4];
#pragma unroll
    for (int i = 0; i < 4; ++i)
#pragma unroll
        for (int j = 0; j < 4; ++j) blin[i][j] = 0.f;

    for (int ch = 0; ch < 8; ++ch) {
        const int col0 = ch * 256;
        float cacc[4][4];
#pragma unroll
        for (int i = 0; i < 4; ++i)
#pragma unroll
            for (int j = 0; j < 4; ++j) cacc[i][j] = 0.f;

        for (int k0 = 0; k0 < 128; k0 += 32) {
            __syncthreads();
            for (int i = tid; i < 32 * 256; i += 256) {
                int kk = i >> 8, jj = i & 255;
                Blds[kk][jj] = W2[(size_t)(k0 + kk) * 2048 + col0 + jj];
            }
            __syncthreads();
#pragma unroll
            for (int kk = 0; kk < 32; ++kk) {
                float bq[4];
#pragma unroll
                for (int j = 0; j < 4; ++j) bq[j] = Blds[kk][cbase + j];
#pragma unroll
                for (int i = 0; i < 4; ++i) {
                    float a = Alds[rbase + i][k0 + kk];
#pragma unroll
                    for (int j = 0; j < 4; ++j) cacc[i][j] += a * bq[j];
                }
            }
        }
        // contract this chunk's C values with re at j_global = ch*16 + jloc
#pragma unroll
        for (int i = 0; i < 4; ++i) {
            float rj = Rlds[rbase + i][ch * 16 + jloc];
#pragma unroll
            for (int j = 0; j < 4; ++j) blin[i][j] += cacc[i][j] * rj;
        }
    }

    // block term partials (distributed over jloc lanes: each handles 8 c's)
#pragma unroll
    for (int cc = 0; cc < 8; ++cc) {
        int c = jloc * 8 + cc;
#pragma unroll
        for (int i = 0; i < 4; ++i) {
            float lv = Alds[rbase + i][c];
            float rv = Rlds[rbase + i][c];
#pragma unroll
            for (int j = 0; j < 4; ++j) {
                int p = pq + j;
                blin[i][j] += lv * Vntn[p * 256 + c] + rv * Vntn[p * 256 + 128 + c];
            }
        }
    }

    // butterfly over the 16 j-lanes (lane bits 2..5)
#pragma unroll
    for (int m = 4; m <= 32; m <<= 1) {
#pragma unroll
        for (int i = 0; i < 4; ++i)
#pragma unroll
            for (int j = 0; j < 4; ++j)
                blin[i][j] += __shfl_xor(blin[i][j], m, 64);
    }

    // tanh, * wfc, reduce over p (lane bits 0..1), sigmoid, store
    float fcv[4];
#pragma unroll
    for (int i = 0; i < 4; ++i) {
        float s = 0.f;
#pragma unroll
        for (int j = 0; j < 4; ++j) {
            int p = pq + j;
            s += tanhf(blin[i][j] + bntn[p]) * wfc[p];
        }
        s += __shfl_xor(s, 1, 64);
        s += __shfl_xor(s, 2, 64);
        fcv[i] = s;
    }
    if (lane == 0) {
        float b0 = bfc[0];
#pragma unroll
        for (int i = 0; i < 4; ++i) {
            float o = 1.f / (1.f + __expf(-(fcv[i] + b0)));
            out[row0 + rbase + i] = o;
        }
    }
}

extern "C" void kernel_launch(void* const* d_in, const int* in_sizes, int n_in,
                              void* d_out, int out_size, void* d_ws, size_t ws_size,
                              hipStream_t stream)
{
    const int* left_x      = (const int*)d_in[0];
    const int* right_x     = (const int*)d_in[2];
    const int* left_batch  = (const int*)d_in[4];
    const int* right_batch = (const int*)d_in[5];
    const int* anc_d  = (const int*)d_in[8];
    const int* leaf_d = (const int*)d_in[9];
    const int* anc_p  = (const int*)d_in[10];
    const int* leaf_p = (const int*)d_in[11];
    const int* anc_a  = (const int*)d_in[12];
    const int* leaf_a = (const int*)d_in[13];
    const float* emb_d = (const float*)d_in[14];
    const float* emb_p = (const float*)d_in[15];
    const float* emb_a = (const float*)d_in[16];
    const float* Wl_d = (const float*)d_in[17];
    const float* bl_d = (const float*)d_in[18];
    const float* ap_d = (const float*)d_in[19];
    const float* Wl_p = (const float*)d_in[20];
    const float* bl_p = (const float*)d_in[21];
    const float* ap_p = (const float*)d_in[22];
    const float* Wl_a = (const float*)d_in[23];
    const float* bl_a = (const float*)d_in[24];
    const float* ap_a = (const float*)d_in[25];
    const float* W_ntn = (const float*)d_in[26];
    const float* V_ntn = (const float*)d_in[27];
    const float* b_ntn = (const float*)d_in[28];
    const float* w_fc  = (const float*)d_in[29];
    const float* b_fc  = (const float*)d_in[30];
    float* out = (float*)d_out;

    float* ws = (float*)d_ws;
    float* s_sum   = ws;                                   // 64 floats (16 used)
    float* le      = ws + 64;                              // 4096*128
    float* re      = le + (size_t)BB * HID;                // 4096*128
    float* all_emb = re + (size_t)BB * HID;                // 18000*128
    bf16*  U       = (bf16*)(all_emb + (size_t)(VD + VP + VA) * HID);  // 23400*256 bf16
    bf16*  U_d = U;
    bf16*  U_p = U_d + (size_t)NGD * 256;
    bf16*  U_a = U_p + (size_t)NGP * 256;

    stage1_gemm<<<(NGD + 31) / 32, 256, 0, stream>>>(emb_d, Wl_d, U_d, NGD);
    stage1_gemm<<<(NGP + 31) / 32, 256, 0, stream>>>(emb_p, Wl_p, U_p, NGP);
    stage1_gemm<<<(NGA + 31) / 32, 256, 0, stream>>>(emb_a, Wl_a, U_a, NGA);

    hipMemsetAsync(s_sum, 0, 16 * sizeof(float), stream);

    aw_kernel<4><<<256, 256, 0, stream>>>(U_d, anc_d, leaf_d, bl_d, ap_d, s_sum + 0, VD);
    aw_kernel<4><<<256, 256, 0, stream>>>(U_p, anc_p, leaf_p, bl_p, ap_p, s_sum + 4, VP);
    aw_kernel<5><<<256, 256, 0, stream>>>(U_a, anc_a, leaf_a, bl_a, ap_a, s_sum + 8, VA);

    allemb_kernel<4><<<256, 256, 0, stream>>>(emb_d, anc_d, s_sum + 0, all_emb, VD);
    allemb_kernel<4><<<256, 256, 0, stream>>>(emb_p, anc_p, s_sum + 4,
                                              all_emb + (size_t)VD * HID, VP);
    allemb_kernel<5><<<256, 256, 0, stream>>>(emb_a, anc_a, s_sum + 8,
                                              all_emb + (size_t)(VD + VP) * HID, VA);

    segsum_kernel<<<BB, 128, 0, stream>>>(all_emb, left_x, left_batch, le);
    segsum_kernel<<<BB, 128, 0, stream>>>(all_emb, right_x, right_batch, re);

    ntn_fused<<<BB / 16, 256, 0, stream>>>(le, re, W_ntn, V_ntn, b_ntn, w_fc, b_fc, out);
}

// Round 3
// 286.966 us; speedup vs baseline: 1.8629x; 1.8629x over previous
//
#include <hip/hip_runtime.h>
#include <hip/hip_bf16.h>

typedef __hip_bfloat16 bf16;

#define HID 128
#define PD  16
#define BB  4096
#define TT  262144
#define VD  10000
#define VP  4000
#define VA  4000
#define NGD 13000
#define NGP 5200
#define NGA 5200

#define NB_D ((NGD + 31) / 32)   // 407
#define NB_P ((NGP + 31) / 32)   // 163
#define NB_A ((NGA + 31) / 32)   // 163

__device__ __forceinline__ float2 bf2x(unsigned int u) {
    float lo = __uint_as_float(u << 16);
    float hi = __uint_as_float(u & 0xffff0000u);
    return make_float2(lo, hi);
}

union Pack4 { bf16 h[4]; uint2 u; };

// ---------------- K1 body: U[g,jj] = sum_k emb[g,k] * Bmat[k,jj]  (f32 in, bf16 out)
__device__ __forceinline__ void stage1_body(
    float (*Alds)[33], float (*Blds)[260],
    const float* __restrict__ emb, const float* __restrict__ Wl,
    bf16* __restrict__ U, int NG, int blk)
{
    const int tid  = threadIdx.x;
    const int row0 = blk * 32;
    const int rbase = (tid >> 6) * 8;
    const int cbase = (tid & 63) * 4;
    float acc[8][4];
#pragma unroll
    for (int i = 0; i < 8; ++i)
#pragma unroll
        for (int j = 0; j < 4; ++j) acc[i][j] = 0.f;

    for (int k0 = 0; k0 < 128; k0 += 32) {
        {
            int i = tid;
#pragma unroll
            for (int it = 0; it < 4; ++it) {
                int r = i >> 5, kk = i & 31;
                int g = row0 + r;
                Alds[r][kk] = (g < NG) ? emb[(size_t)g * HID + k0 + kk] : 0.f;
                i += 256;
            }
        }
        {
            int i = tid;
#pragma unroll
            for (int it = 0; it < 32; ++it) {
                int kk = i & 31, jj = i >> 5;
                int k = k0 + kk;
                float v = (jj < 128) ? Wl[jj * 256 + k] : Wl[(jj - 128) * 256 + 128 + k];
                Blds[kk][jj] = v;
                i += 256;
            }
        }
        __syncthreads();
#pragma unroll
        for (int kk = 0; kk < 32; ++kk) {
            float bq[4];
#pragma unroll
            for (int j = 0; j < 4; ++j) bq[j] = Blds[kk][cbase + j];
#pragma unroll
            for (int i = 0; i < 8; ++i) {
                float a = Alds[rbase + i][kk];
#pragma unroll
                for (int j = 0; j < 4; ++j) acc[i][j] += a * bq[j];
            }
        }
        __syncthreads();
    }
#pragma unroll
    for (int i = 0; i < 8; ++i) {
        int g = row0 + rbase + i;
        if (g < NG) {
            Pack4 pk;
#pragma unroll
            for (int j = 0; j < 4; ++j) pk.h[j] = __float2bfloat16(acc[i][j]);
            *reinterpret_cast<uint2*>(&U[(size_t)g * 256 + cbase]) = pk.u;
        }
    }
}

__global__ __launch_bounds__(256) void stage1_all(
    const float* __restrict__ emb_d, const float* __restrict__ Wl_d, bf16* __restrict__ U_d,
    const float* __restrict__ emb_p, const float* __restrict__ Wl_p, bf16* __restrict__ U_p,
    const float* __restrict__ emb_a, const float* __restrict__ Wl_a, bf16* __restrict__ U_a)
{
    __shared__ float Alds[32][33];
    __shared__ float Blds[32][260];
    int bx = blockIdx.x;
    if (bx < NB_D)            stage1_body(Alds, Blds, emb_d, Wl_d, U_d, NGD, bx);
    else if (bx < NB_D + NB_P) stage1_body(Alds, Blds, emb_p, Wl_p, U_p, NGP, bx - NB_D);
    else                       stage1_body(Alds, Blds, emb_a, Wl_a, U_a, NGA, bx - NB_D - NB_P);
}

// ---------------- K2 body: aw + softmax + accumulate global s_sum
template <int L>
__device__ __forceinline__ void aw_body(
    float* sacc,
    const bf16* __restrict__ U, const int* __restrict__ anc, const int* __restrict__ leaf,
    const float* __restrict__ bl, const float* __restrict__ ap,
    float* __restrict__ s_out, int V, int blk, int nblk)
{
    const int tid  = threadIdx.x;
    const int lane = tid & 63;
    const int wid  = blk * 4 + (tid >> 6);
    const int nw   = nblk * 4;
    const float2 blv = *reinterpret_cast<const float2*>(bl + 2 * lane);
    const float2 apv = *reinterpret_cast<const float2*>(ap + 2 * lane);
    const unsigned int* Uw = reinterpret_cast<const unsigned int*>(U);
    float wacc[L];
#pragma unroll
    for (int l = 0; l < L; ++l) wacc[l] = 0.f;

    for (int v = wid; v < V; v += nw) {
        float aw[L];
#pragma unroll
        for (int l = 0; l < L; ++l) {
            int a = anc[v * L + l];
            int f = leaf[v * L + l];
            float2 a2 = bf2x(Uw[(size_t)a * 128 + lane]);
            float2 l2 = bf2x(Uw[(size_t)f * 128 + 64 + lane]);
            float t0 = tanhf(a2.x + l2.x + blv.x);
            float t1 = tanhf(a2.y + l2.y + blv.y);
            float p = t0 * apv.x + t1 * apv.y;
#pragma unroll
            for (int off = 32; off; off >>= 1) p += __shfl_xor(p, off, 64);
            aw[l] = p;
        }
        float m = aw[0];
#pragma unroll
        for (int l = 1; l < L; ++l) m = fmaxf(m, aw[l]);
        float den = 0.f, e[L];
#pragma unroll
        for (int l = 0; l < L; ++l) { e[l] = __expf(aw[l] - m); den += e[l]; }
        float inv = 1.f / den;
#pragma unroll
        for (int l = 0; l < L; ++l) wacc[l] += e[l] * inv;
    }
    if (lane == 0) {
#pragma unroll
        for (int l = 0; l < L; ++l) atomicAdd(&sacc[l], wacc[l]);
    }
    __syncthreads();
    if (tid < L) atomicAdd(&s_out[tid], sacc[tid]);
}

__global__ __launch_bounds__(256) void aw_all(
    const bf16* __restrict__ U_d, const int* __restrict__ anc_d, const int* __restrict__ leaf_d,
    const float* __restrict__ bl_d, const float* __restrict__ ap_d,
    const bf16* __restrict__ U_p, const int* __restrict__ anc_p, const int* __restrict__ leaf_p,
    const float* __restrict__ bl_p, const float* __restrict__ ap_p,
    const bf16* __restrict__ U_a, const int* __restrict__ anc_a, const int* __restrict__ leaf_a,
    const float* __restrict__ bl_a, const float* __restrict__ ap_a,
    float* __restrict__ s_sum)
{
    __shared__ float sacc[5];
    const int tid = threadIdx.x;
    if (tid < 5) sacc[tid] = 0.f;
    __syncthreads();
    int bx = blockIdx.x;
    if (bx < 512)      aw_body<4>(sacc, U_d, anc_d, leaf_d, bl_d, ap_d, s_sum + 0, VD, bx, 512);
    else if (bx < 768) aw_body<4>(sacc, U_p, anc_p, leaf_p, bl_p, ap_p, s_sum + 4, VP, bx - 512, 256);
    else               aw_body<5>(sacc, U_a, anc_a, leaf_a, bl_a, ap_a, s_sum + 8, VA, bx - 768, 256);
}

// ---------------- K3 body: all_emb[v,:] = sum_l s[l] * emb[anc[v,l],:]
template <int L>
__device__ __forceinline__ void allemb_body(
    const float* __restrict__ emb, const int* __restrict__ anc,
    const float* __restrict__ s, float* __restrict__ out, int V, int blk, int nblk)
{
    const int tid  = threadIdx.x;
    const int lane = tid & 63;
    const int wid  = blk * 4 + (tid >> 6);
    const int nw   = nblk * 4;
    float sv[L];
#pragma unroll
    for (int l = 0; l < L; ++l) sv[l] = s[l];
    for (int v = wid; v < V; v += nw) {
        float ax = 0.f, ay = 0.f;
#pragma unroll
        for (int l = 0; l < L; ++l) {
            const float2* e = reinterpret_cast<const float2*>(emb + (size_t)anc[v * L + l] * HID);
            float2 val = e[lane];
            ax += sv[l] * val.x;
            ay += sv[l] * val.y;
        }
        reinterpret_cast<float2*>(out + (size_t)v * HID)[lane] = make_float2(ax, ay);
    }
}

__global__ __launch_bounds__(256) void allemb_all(
    const float* __restrict__ emb_d, const int* __restrict__ anc_d,
    const float* __restrict__ emb_p, const int* __restrict__ anc_p,
    const float* __restrict__ emb_a, const int* __restrict__ anc_a,
    const float* __restrict__ s_sum, float* __restrict__ all_emb)
{
    int bx = blockIdx.x;
    if (bx < 512)
        allemb_body<4>(emb_d, anc_d, s_sum + 0, all_emb, VD, bx, 512);
    else if (bx < 768)
        allemb_body<4>(emb_p, anc_p, s_sum + 4, all_emb + (size_t)VD * HID, VP, bx - 512, 256);
    else
        allemb_body<5>(emb_a, anc_a, s_sum + 8, all_emb + (size_t)(VD + VP) * HID, VA, bx - 768, 256);
}

// ---------------- K4: segment sum over sorted batch ids, left+right in one grid
__global__ __launch_bounds__(128) void segsum_both(
    const float* __restrict__ all_emb,
    const int* __restrict__ lx, const int* __restrict__ lb, float* __restrict__ le,
    const int* __restrict__ rx, const int* __restrict__ rb, float* __restrict__ re)
{
    const int b   = blockIdx.x & (BB - 1);
    const int tid = threadIdx.x;
    const int* x;
    const int* batch;
    float* out;
    if (blockIdx.x < BB) { x = lx; batch = lb; out = le; }
    else                 { x = rx; batch = rb; out = re; }
    int l = 0, r = TT;
    while (l < r) { int m = (l + r) >> 1; if (batch[m] < b) l = m + 1; else r = m; }
    const int lo = l;
    r = TT;
    while (l < r) { int m = (l + r) >> 1; if (batch[m] < b + 1) l = m + 1; else r = m; }
    const int hi = l;
    float acc = 0.f;
    int t = lo;
    for (; t + 3 < hi; t += 4) {
        int i0 = x[t], i1 = x[t + 1], i2 = x[t + 2], i3 = x[t + 3];
        acc += all_emb[(size_t)i0 * HID + tid];
        acc += all_emb[(size_t)i1 * HID + tid];
        acc += all_emb[(size_t)i2 * HID + tid];
        acc += all_emb[(size_t)i3 * HID + tid];
    }
    for (; t < hi; ++t) acc += all_emb[(size_t)x[t] * HID + tid];
    out[(size_t)b * HID + tid] = acc;
}

// ---------------- K5a: NTN GEMM tile + contraction with re -> partial bilinear
// grid (64, 8). Block computes C-tile [64 rows x 256 cols], cols = 16 j x 16 p,
// contracts with re over its 16 j's, writes part[by][b][p] (deterministic, no atomics).
__global__ __launch_bounds__(256) void ntn_part(
    const float* __restrict__ le, const float* __restrict__ re,
    const float* __restrict__ W2, float* __restrict__ part)
{
    __shared__ float Alds[32][68];      // [kk][row], padded for 16B-aligned b128
    __shared__ float Blds[32 * 264];    // [kk][col], stride 264
    __shared__ float Rlds[64][17];      // [row][jloc]
    const int tid   = threadIdx.x;
    const int row0  = blockIdx.x * 64;
    const int col0  = blockIdx.y * 256;
    const int lane5 = tid & 31;
    const int rbase = (tid >> 5) * 8;
    const int cbase = lane5 * 8;
    float acc[8][8];
#pragma unroll
    for (int i = 0; i < 8; ++i)
#pragma unroll
        for (int j = 0; j < 8; ++j) acc[i][j] = 0.f;

    for (int i = tid; i < 64 * 16; i += 256) {
        int rr = i >> 4, jl = i & 15;
        Rlds[rr][jl] = re[(size_t)(row0 + rr) * HID + blockIdx.y * 16 + jl];
    }

    for (int k0 = 0; k0 < 128; k0 += 32) {
        __syncthreads();
        for (int i = tid; i < 64 * 32; i += 256) {
            int rr = i >> 5, kk = i & 31;
            Alds[kk][rr] = le[(size_t)(row0 + rr) * HID + k0 + kk];
        }
        for (int i = tid; i < 32 * 64; i += 256) {
            int kk = i >> 6, j4 = (i & 63) * 4;
            float4 v = *reinterpret_cast<const float4*>(&W2[(size_t)(k0 + kk) * 2048 + col0 + j4]);
            *reinterpret_cast<float4*>(&Blds[kk * 264 + j4]) = v;
        }
        __syncthreads();
#pragma unroll
        for (int kk = 0; kk < 32; ++kk) {
            float4 a0 = *reinterpret_cast<const float4*>(&Alds[kk][rbase]);
            float4 a1 = *reinterpret_cast<const float4*>(&Alds[kk][rbase + 4]);
            float4 b0 = *reinterpret_cast<const float4*>(&Blds[kk * 264 + cbase]);
            float4 b1 = *reinterpret_cast<const float4*>(&Blds[kk * 264 + cbase + 4]);
            float av[8] = {a0.x, a0.y, a0.z, a0.w, a1.x, a1.y, a1.z, a1.w};
            float bv[8] = {b0.x, b0.y, b0.z, b0.w, b1.x, b1.y, b1.z, b1.w};
#pragma unroll
            for (int i = 0; i < 8; ++i)
#pragma unroll
                for (int j = 0; j < 8; ++j) acc[i][j] += av[i] * bv[j];
        }
    }

    // contract with re over this block's 16 j's, reduce across jloc lanes
    const int jloc = lane5 >> 1;
    const int pq   = (tid & 1) * 8;
#pragma unroll
    for (int i = 0; i < 8; ++i) {
        int row = rbase + i;
        float rj = Rlds[row][jloc];
        float pb[8];
#pragma unroll
        for (int j = 0; j < 8; ++j) pb[j] = acc[i][j] * rj;
#pragma unroll
        for (int m = 2; m <= 16; m <<= 1) {
#pragma unroll
            for (int j = 0; j < 8; ++j) pb[j] += __shfl_xor(pb[j], m, 64);
        }
        if ((tid & 30) == 0) {   // lanes 0,1,32,33
            size_t base = ((size_t)blockIdx.y * BB + row0 + row) * PD + pq;
            *reinterpret_cast<float4*>(&part[base])     = make_float4(pb[0], pb[1], pb[2], pb[3]);
            *reinterpret_cast<float4*>(&part[base + 4]) = make_float4(pb[4], pb[5], pb[6], pb[7]);
        }
    }
}

// ---------------- K5b: sum partials + block term + tanh + fc + sigmoid
__global__ __launch_bounds__(256) void ntn_epi(
    const float* __restrict__ part, const float* __restrict__ le, const float* __restrict__ re,
    const float* __restrict__ Vntn, const float* __restrict__ bntn,
    const float* __restrict__ wfc, const float* __restrict__ bfc,
    float* __restrict__ out)
{
    __shared__ float Vlds[16 * 257];
    __shared__ float LE[16 * 128];
    __shared__ float RE[16 * 128];
    const int tid = threadIdx.x;
    const int b0  = blockIdx.x * 16;
    for (int i = tid; i < 4096; i += 256) Vlds[(i >> 8) * 257 + (i & 255)] = Vntn[i];
    for (int i = tid; i < 2048; i += 256) {
        LE[i] = le[(size_t)b0 * HID + i];
        RE[i] = re[(size_t)b0 * HID + i];
    }
    __syncthreads();
    const int bl = tid >> 4, p = tid & 15;
    const int b  = b0 + bl;
    float bil = 0.f;
#pragma unroll
    for (int by = 0; by < 8; ++by) bil += part[((size_t)by * BB + b) * PD + p];
    float s = bil + bntn[p];
    const float* Vp   = &Vlds[p * 257];
    const float* lrow = &LE[bl * 128];
    const float* rrow = &RE[bl * 128];
#pragma unroll 8
    for (int c = 0; c < 128; ++c) s += lrow[c] * Vp[c] + rrow[c] * Vp[128 + c];
    float x = tanhf(s) * wfc[p];
    x += __shfl_xor(x, 1, 64);
    x += __shfl_xor(x, 2, 64);
    x += __shfl_xor(x, 4, 64);
    x += __shfl_xor(x, 8, 64);
    if (p == 0) out[b] = 1.f / (1.f + __expf(-(x + bfc[0])));
}

extern "C" void kernel_launch(void* const* d_in, const int* in_sizes, int n_in,
                              void* d_out, int out_size, void* d_ws, size_t ws_size,
                              hipStream_t stream)
{
    const int* left_x      = (const int*)d_in[0];
    const int* right_x     = (const int*)d_in[2];
    const int* left_batch  = (const int*)d_in[4];
    const int* right_batch = (const int*)d_in[5];
    const int* anc_d  = (const int*)d_in[8];
    const int* leaf_d = (const int*)d_in[9];
    const int* anc_p  = (const int*)d_in[10];
    const int* leaf_p = (const int*)d_in[11];
    const int* anc_a  = (const int*)d_in[12];
    const int* leaf_a = (const int*)d_in[13];
    const float* emb_d = (const float*)d_in[14];
    const float* emb_p = (const float*)d_in[15];
    const float* emb_a = (const float*)d_in[16];
    const float* Wl_d = (const float*)d_in[17];
    const float* bl_d = (const float*)d_in[18];
    const float* ap_d = (const float*)d_in[19];
    const float* Wl_p = (const float*)d_in[20];
    const float* bl_p = (const float*)d_in[21];
    const float* ap_p = (const float*)d_in[22];
    const float* Wl_a = (const float*)d_in[23];
    const float* bl_a = (const float*)d_in[24];
    const float* ap_a = (const float*)d_in[25];
    const float* W_ntn = (const float*)d_in[26];
    const float* V_ntn = (const float*)d_in[27];
    const float* b_ntn = (const float*)d_in[28];
    const float* w_fc  = (const float*)d_in[29];
    const float* b_fc  = (const float*)d_in[30];
    float* out = (float*)d_out;

    float* ws = (float*)d_ws;
    float* s_sum   = ws;                                    // 64 floats (13 used)
    float* le      = ws + 64;                               // 4096*128
    float* re      = le + (size_t)BB * HID;                 // 4096*128
    float* all_emb = re + (size_t)BB * HID;                 // 18000*128
    float* part    = all_emb + (size_t)(VD + VP + VA) * HID;// 8*4096*16
    bf16*  U       = (bf16*)(part + (size_t)8 * BB * PD);   // 23400*256 bf16
    bf16*  U_d = U;
    bf16*  U_p = U_d + (size_t)NGD * 256;
    bf16*  U_a = U_p + (size_t)NGP * 256;

    stage1_all<<<NB_D + NB_P + NB_A, 256, 0, stream>>>(
        emb_d, Wl_d, U_d, emb_p, Wl_p, U_p, emb_a, Wl_a, U_a);

    hipMemsetAsync(s_sum, 0, 16 * sizeof(float), stream);

    aw_all<<<1024, 256, 0, stream>>>(
        U_d, anc_d, leaf_d, bl_d, ap_d,
        U_p, anc_p, leaf_p, bl_p, ap_p,
        U_a, anc_a, leaf_a, bl_a, ap_a, s_sum);

    allemb_all<<<1024, 256, 0, stream>>>(
        emb_d, anc_d, emb_p, anc_p, emb_a, anc_a, s_sum, all_emb);

    segsum_both<<<2 * BB, 128, 0, stream>>>(
        all_emb, left_x, left_batch, le, right_x, right_batch, re);

    ntn_part<<<dim3(64, 8), 256, 0, stream>>>(le, re, W_ntn, part);

    ntn_epi<<<BB / 16, 256, 0, stream>>>(part, le, re, V_ntn, b_ntn, w_fc, b_fc, out);
}

// Round 4
// 270.451 us; speedup vs baseline: 1.9766x; 1.0611x over previous
//
#include <hip/hip_runtime.h>
#include <hip/hip_bf16.h>

typedef __hip_bfloat16 bf16;
typedef __attribute__((ext_vector_type(8))) short bf16x8;
typedef __attribute__((ext_vector_type(4))) float f32x4;

#define HID 128
#define PD  16
#define BB  4096
#define TT  262144
#define VD  10000
#define VP  4000
#define VA  4000
#define NGD 13000
#define NGP 5200
#define NGA 5200

#define NB_D ((NGD + 31) / 32)   // 407
#define NB_P ((NGP + 31) / 32)   // 163
#define NB_A ((NGA + 31) / 32)   // 163

__device__ __forceinline__ float2 bf2x(unsigned int u) {
    float lo = __uint_as_float(u << 16);
    float hi = __uint_as_float(u & 0xffff0000u);
    return make_float2(lo, hi);
}

union Pack2 { bf16 h[2]; unsigned int u; };
__device__ __forceinline__ unsigned int pk2(float a, float b) {
    Pack2 p; p.h[0] = __float2bfloat16(a); p.h[1] = __float2bfloat16(b); return p.u;
}

// ---------------- K0: prep W fragments.
// B3 fragment-major: B3[((jt*4+q)*64 + lane)*8 + jj] = Bmat[q*32+(lane>>4)*8+jj][jt*16+(lane&15)]
// Bmat[k][c] = (c<128) ? Wl[c*256+k] : Wl[(c-128)*256+128+k]
__global__ __launch_bounds__(256) void prep_b3(
    const float* __restrict__ Wl_d, const float* __restrict__ Wl_p, const float* __restrict__ Wl_a,
    bf16* __restrict__ B3_d, bf16* __restrict__ B3_p, bf16* __restrict__ B3_a)
{
    const int sec = blockIdx.x >> 4, jt = blockIdx.x & 15;
    const float* Wl = (sec == 0) ? Wl_d : (sec == 1) ? Wl_p : Wl_a;
    bf16* B3 = (sec == 0) ? B3_d : (sec == 1) ? B3_p : B3_a;
    const int tid = threadIdx.x;
    const int q = tid >> 6, lane = tid & 63;
    const int quad = lane >> 4, m = lane & 15;
    const int col = jt * 16 + m;
    const float* src = (col < 128) ? (Wl + col * 256) : (Wl + (col - 128) * 256 + 128);
    unsigned int pk[4];
#pragma unroll
    for (int jp = 0; jp < 4; ++jp) {
        int k0 = q * 32 + quad * 8 + 2 * jp;
        pk[jp] = pk2(src[k0], src[k0 + 1]);
    }
    uint4 val = make_uint4(pk[0], pk[1], pk[2], pk[3]);
    *reinterpret_cast<uint4*>(B3 + ((size_t)(jt * 4 + q) * 64 + lane) * 8) = val;
}

// ---------------- K1: U[g, 0..255] via bf16 MFMA, 32 rows x 256 cols per block.
// A-operand = W frags (m = j-offset), B-operand = emb frags (n = g-offset)
// => D(row=quad*4+reg, col=lane&15) = U[g0+col][jt*16+quad*4+reg]: packed 8B stores.
__device__ __forceinline__ void stage1_body(
    unsigned short (*Abf)[136],
    const float* __restrict__ emb, const bf16* __restrict__ B3,
    bf16* __restrict__ U, int NG, int blk)
{
    const int tid  = threadIdx.x;
    const int row0 = blk * 32;
    // stage 32 emb rows f32 -> bf16 LDS
    {
        const int r = tid >> 3, seg = tid & 7;
        const int g = row0 + r;
        float v[16];
        if (g < NG) {
            const float4* src = reinterpret_cast<const float4*>(emb + (size_t)g * HID + seg * 16);
#pragma unroll
            for (int i = 0; i < 4; ++i) {
                float4 f = src[i];
                v[4 * i] = f.x; v[4 * i + 1] = f.y; v[4 * i + 2] = f.z; v[4 * i + 3] = f.w;
            }
        } else {
#pragma unroll
            for (int i = 0; i < 16; ++i) v[i] = 0.f;
        }
        unsigned int pk[8];
#pragma unroll
        for (int i = 0; i < 8; ++i) pk[i] = pk2(v[2 * i], v[2 * i + 1]);
        uint4* dst = reinterpret_cast<uint4*>(&Abf[r][seg * 16]);
        dst[0] = make_uint4(pk[0], pk[1], pk[2], pk[3]);
        dst[1] = make_uint4(pk[4], pk[5], pk[6], pk[7]);
    }
    __syncthreads();

    const int lane   = tid & 63;
    const int w      = tid >> 6;
    const int gtile  = w & 1;
    const int jstrip = w >> 1;
    const int lrow   = gtile * 16 + (lane & 15);
    const int koff   = (lane >> 4) * 8;   // quad*8
    const bf16x8* B3f = reinterpret_cast<const bf16x8*>(B3);

    f32x4 acc[8];
#pragma unroll
    for (int t = 0; t < 8; ++t) acc[t] = (f32x4){0.f, 0.f, 0.f, 0.f};

#pragma unroll
    for (int q = 0; q < 4; ++q) {
        bf16x8 ef = *reinterpret_cast<const bf16x8*>(&Abf[lrow][q * 32 + koff]);
#pragma unroll
        for (int t = 0; t < 8; ++t) {
            int jt = jstrip * 8 + t;
            bf16x8 wf = B3f[(jt * 4 + q) * 64 + lane];
            acc[t] = __builtin_amdgcn_mfma_f32_16x16x32_bf16(wf, ef, acc[t], 0, 0, 0);
        }
    }

    const int g = row0 + gtile * 16 + (lane & 15);
    if (g < NG) {
        const int quad = lane >> 4;
        bf16* Ur = U + (size_t)g * 256;
#pragma unroll
        for (int t = 0; t < 8; ++t) {
            int j0 = (jstrip * 8 + t) * 16 + quad * 4;
            uint2 st = make_uint2(pk2(acc[t].x, acc[t].y), pk2(acc[t].z, acc[t].w));
            *reinterpret_cast<uint2*>(Ur + j0) = st;
        }
    }
}

__global__ __launch_bounds__(256) void stage1_mfma(
    const float* __restrict__ emb_d, const bf16* __restrict__ B3_d, bf16* __restrict__ U_d,
    const float* __restrict__ emb_p, const bf16* __restrict__ B3_p, bf16* __restrict__ U_p,
    const float* __restrict__ emb_a, const bf16* __restrict__ B3_a, bf16* __restrict__ U_a)
{
    __shared__ unsigned short Abf[32][136];
    int bx = blockIdx.x;
    if (bx < NB_D)             stage1_body(Abf, emb_d, B3_d, U_d, NGD, bx);
    else if (bx < NB_D + NB_P) stage1_body(Abf, emb_p, B3_p, U_p, NGP, bx - NB_D);
    else                       stage1_body(Abf, emb_a, B3_a, U_a, NGA, bx - NB_D - NB_P);
}

// ---------------- K2 body: aw + softmax + accumulate global s_sum
template <int L>
__device__ __forceinline__ void aw_body(
    float* sacc,
    const bf16* __restrict__ U, const int* __restrict__ anc, const int* __restrict__ leaf,
    const float* __restrict__ bl, const float* __restrict__ ap,
    float* __restrict__ s_out, int V, int blk, int nblk)
{
    const int tid  = threadIdx.x;
    const int lane = tid & 63;
    const int wid  = blk * 4 + (tid >> 6);
    const int nw   = nblk * 4;
    const float2 blv = *reinterpret_cast<const float2*>(bl + 2 * lane);
    const float2 apv = *reinterpret_cast<const float2*>(ap + 2 * lane);
    const unsigned int* Uw = reinterpret_cast<const unsigned int*>(U);
    float wacc[L];
#pragma unroll
    for (int l = 0; l < L; ++l) wacc[l] = 0.f;

    for (int v = wid; v < V; v += nw) {
        float aw[L];
#pragma unroll
        for (int l = 0; l < L; ++l) {
            int a = anc[v * L + l];
            int f = leaf[v * L + l];
            float2 a2 = bf2x(Uw[(size_t)a * 128 + lane]);
            float2 l2 = bf2x(Uw[(size_t)f * 128 + 64 + lane]);
            float t0 = tanhf(a2.x + l2.x + blv.x);
            float t1 = tanhf(a2.y + l2.y + blv.y);
            float p = t0 * apv.x + t1 * apv.y;
#pragma unroll
            for (int off = 32; off; off >>= 1) p += __shfl_xor(p, off, 64);
            aw[l] = p;
        }
        float m = aw[0];
#pragma unroll
        for (int l = 1; l < L; ++l) m = fmaxf(m, aw[l]);
        float den = 0.f, e[L];
#pragma unroll
        for (int l = 0; l < L; ++l) { e[l] = __expf(aw[l] - m); den += e[l]; }
        float inv = 1.f / den;
#pragma unroll
        for (int l = 0; l < L; ++l) wacc[l] += e[l] * inv;
    }
    if (lane == 0) {
#pragma unroll
        for (int l = 0; l < L; ++l) atomicAdd(&sacc[l], wacc[l]);
    }
    __syncthreads();
    if (tid < L) atomicAdd(&s_out[tid], sacc[tid]);
}

__global__ __launch_bounds__(256) void aw_all(
    const bf16* __restrict__ U_d, const int* __restrict__ anc_d, const int* __restrict__ leaf_d,
    const float* __restrict__ bl_d, const float* __restrict__ ap_d,
    const bf16* __restrict__ U_p, const int* __restrict__ anc_p, const int* __restrict__ leaf_p,
    const float* __restrict__ bl_p, const float* __restrict__ ap_p,
    const bf16* __restrict__ U_a, const int* __restrict__ anc_a, const int* __restrict__ leaf_a,
    const float* __restrict__ bl_a, const float* __restrict__ ap_a,
    float* __restrict__ s_sum)
{
    __shared__ float sacc[5];
    const int tid = threadIdx.x;
    if (tid < 5) sacc[tid] = 0.f;
    __syncthreads();
    int bx = blockIdx.x;
    if (bx < 512)      aw_body<4>(sacc, U_d, anc_d, leaf_d, bl_d, ap_d, s_sum + 0, VD, bx, 512);
    else if (bx < 768) aw_body<4>(sacc, U_p, anc_p, leaf_p, bl_p, ap_p, s_sum + 4, VP, bx - 512, 256);
    else               aw_body<5>(sacc, U_a, anc_a, leaf_a, bl_a, ap_a, s_sum + 8, VA, bx - 768, 256);
}

// ---------------- K3 body: all_emb[v,:] = sum_l s[l] * emb[anc[v,l],:]
template <int L>
__device__ __forceinline__ void allemb_body(
    const float* __restrict__ emb, const int* __restrict__ anc,
    const float* __restrict__ s, float* __restrict__ out, int V, int blk, int nblk)
{
    const int tid  = threadIdx.x;
    const int lane = tid & 63;
    const int wid  = blk * 4 + (tid >> 6);
    const int nw   = nblk * 4;
    float sv[L];
#pragma unroll
    for (int l = 0; l < L; ++l) sv[l] = s[l];
    for (int v = wid; v < V; v += nw) {
        float ax = 0.f, ay = 0.f;
#pragma unroll
        for (int l = 0; l < L; ++l) {
            const float2* e = reinterpret_cast<const float2*>(emb + (size_t)anc[v * L + l] * HID);
            float2 val = e[lane];
            ax += sv[l] * val.x;
            ay += sv[l] * val.y;
        }
        reinterpret_cast<float2*>(out + (size_t)v * HID)[lane] = make_float2(ax, ay);
    }
}

__global__ __launch_bounds__(256) void allemb_all(
    const float* __restrict__ emb_d, const int* __restrict__ anc_d,
    const float* __restrict__ emb_p, const int* __restrict__ anc_p,
    const float* __restrict__ emb_a, const int* __restrict__ anc_a,
    const float* __restrict__ s_sum, float* __restrict__ all_emb)
{
    int bx = blockIdx.x;
    if (bx < 512)
        allemb_body<4>(emb_d, anc_d, s_sum + 0, all_emb, VD, bx, 512);
    else if (bx < 768)
        allemb_body<4>(emb_p, anc_p, s_sum + 4, all_emb + (size_t)VD * HID, VP, bx - 512, 256);
    else
        allemb_body<5>(emb_a, anc_a, s_sum + 8, all_emb + (size_t)(VD + VP) * HID, VA, bx - 768, 256);
}

// ---------------- K4: segment sum over sorted batch ids, left+right in one grid
__global__ __launch_bounds__(256) void segsum_both(
    const float* __restrict__ all_emb,
    const int* __restrict__ lx, const int* __restrict__ lb, float* __restrict__ le,
    const int* __restrict__ rx, const int* __restrict__ rb, float* __restrict__ re)
{
    __shared__ float sbuf[128];
    const int b   = blockIdx.x & (BB - 1);
    const int tid = threadIdx.x;
    const int* x;
    const int* batch;
    float* out;
    if (blockIdx.x < BB) { x = lx; batch = lb; out = le; }
    else                 { x = rx; batch = rb; out = re; }
    int l = 0, r = TT;
    while (l < r) { int m = (l + r) >> 1; if (batch[m] < b) l = m + 1; else r = m; }
    const int lo = l;
    r = TT;
    while (l < r) { int m = (l + r) >> 1; if (batch[m] < b + 1) l = m + 1; else r = m; }
    const int hi = l;
    const int c = tid & 127, half = tid >> 7;
    float acc = 0.f;
    int t = lo + half;
    for (; t + 6 < hi; t += 8) {
        int i0 = x[t], i1 = x[t + 2], i2 = x[t + 4], i3 = x[t + 6];
        acc += all_emb[(size_t)i0 * HID + c];
        acc += all_emb[(size_t)i1 * HID + c];
        acc += all_emb[(size_t)i2 * HID + c];
        acc += all_emb[(size_t)i3 * HID + c];
    }
    for (; t < hi; t += 2) acc += all_emb[(size_t)x[t] * HID + c];
    if (half == 1) sbuf[c] = acc;
    __syncthreads();
    if (half == 0) out[(size_t)b * HID + c] = acc + sbuf[c];
}

// ---------------- K5a: NTN GEMM tile + contraction with re -> partial bilinear
__global__ __launch_bounds__(256) void ntn_part(
    const float* __restrict__ le, const float* __restrict__ re,
    const float* __restrict__ W2, float* __restrict__ part)
{
    __shared__ float Alds[32][68];
    __shared__ float Blds[32 * 264];
    __shared__ float Rlds[64][17];
    const int tid   = threadIdx.x;
    const int row0  = blockIdx.x * 64;
    const int col0  = blockIdx.y * 256;
    const int lane5 = tid & 31;
    const int rbase = (tid >> 5) * 8;
    const int cbase = lane5 * 8;
    float acc[8][8];
#pragma unroll
    for (int i = 0; i < 8; ++i)
#pragma unroll
        for (int j = 0; j < 8; ++j) acc[i][j] = 0.f;

    for (int i = tid; i < 64 * 16; i += 256) {
        int rr = i >> 4, jl = i & 15;
        Rlds[rr][jl] = re[(size_t)(row0 + rr) * HID + blockIdx.y * 16 + jl];
    }

    for (int k0 = 0; k0 < 128; k0 += 32) {
        __syncthreads();
        for (int i = tid; i < 64 * 32; i += 256) {
            int rr = i >> 5, kk = i & 31;
            Alds[kk][rr] = le[(size_t)(row0 + rr) * HID + k0 + kk];
        }
        for (int i = tid; i < 32 * 64; i += 256) {
            int kk = i >> 6, j4 = (i & 63) * 4;
            float4 v = *reinterpret_cast<const float4*>(&W2[(size_t)(k0 + kk) * 2048 + col0 + j4]);
            *reinterpret_cast<float4*>(&Blds[kk * 264 + j4]) = v;
        }
        __syncthreads();
#pragma unroll
        for (int kk = 0; kk < 32; ++kk) {
            float4 a0 = *reinterpret_cast<const float4*>(&Alds[kk][rbase]);
            float4 a1 = *reinterpret_cast<const float4*>(&Alds[kk][rbase + 4]);
            float4 b0 = *reinterpret_cast<const float4*>(&Blds[kk * 264 + cbase]);
            float4 b1 = *reinterpret_cast<const float4*>(&Blds[kk * 264 + cbase + 4]);
            float av[8] = {a0.x, a0.y, a0.z, a0.w, a1.x, a1.y, a1.z, a1.w};
            float bv[8] = {b0.x, b0.y, b0.z, b0.w, b1.x, b1.y, b1.z, b1.w};
#pragma unroll
            for (int i = 0; i < 8; ++i)
#pragma unroll
                for (int j = 0; j < 8; ++j) acc[i][j] += av[i] * bv[j];
        }
    }

    const int jloc = lane5 >> 1;
    const int pq   = (tid & 1) * 8;
#pragma unroll
    for (int i = 0; i < 8; ++i) {
        int row = rbase + i;
        float rj = Rlds[row][jloc];
        float pb[8];
#pragma unroll
        for (int j = 0; j < 8; ++j) pb[j] = acc[i][j] * rj;
#pragma unroll
        for (int m = 2; m <= 16; m <<= 1) {
#pragma unroll
            for (int j = 0; j < 8; ++j) pb[j] += __shfl_xor(pb[j], m, 64);
        }
        if ((tid & 30) == 0) {
            size_t base = ((size_t)blockIdx.y * BB + row0 + row) * PD + pq;
            *reinterpret_cast<float4*>(&part[base])     = make_float4(pb[0], pb[1], pb[2], pb[3]);
            *reinterpret_cast<float4*>(&part[base + 4]) = make_float4(pb[4], pb[5], pb[6], pb[7]);
        }
    }
}

// ---------------- K5b: sum partials + block term + tanh + fc + sigmoid
__global__ __launch_bounds__(256) void ntn_epi(
    const float* __restrict__ part, const float* __restrict__ le, const float* __restrict__ re,
    const float* __restrict__ Vntn, const float* __restrict__ bntn,
    const float* __restrict__ wfc, const float* __restrict__ bfc,
    float* __restrict__ out)
{
    __shared__ float Vlds[16 * 257];
    __shared__ float LE[16 * 128];
    __shared__ float RE[16 * 128];
    const int tid = threadIdx.x;
    const int b0  = blockIdx.x * 16;
    for (int i = tid; i < 4096; i += 256) Vlds[(i >> 8) * 257 + (i & 255)] = Vntn[i];
    for (int i = tid; i < 2048; i += 256) {
        LE[i] = le[(size_t)b0 * HID + i];
        RE[i] = re[(size_t)b0 * HID + i];
    }
    __syncthreads();
    const int bl = tid >> 4, p = tid & 15;
    const int b  = b0 + bl;
    float bil = 0.f;
#pragma unroll
    for (int by = 0; by < 8; ++by) bil += part[((size_t)by * BB + b) * PD + p];
    float s = bil + bntn[p];
    const float* Vp   = &Vlds[p * 257];
    const float* lrow = &LE[bl * 128];
    const float* rrow = &RE[bl * 128];
#pragma unroll 8
    for (int c = 0; c < 128; ++c) s += lrow[c] * Vp[c] + rrow[c] * Vp[128 + c];
    float x = tanhf(s) * wfc[p];
    x += __shfl_xor(x, 1, 64);
    x += __shfl_xor(x, 2, 64);
    x += __shfl_xor(x, 4, 64);
    x += __shfl_xor(x, 8, 64);
    if (p == 0) out[b] = 1.f / (1.f + __expf(-(x + bfc[0])));
}

extern "C" void kernel_launch(void* const* d_in, const int* in_sizes, int n_in,
                              void* d_out, int out_size, void* d_ws, size_t ws_size,
                              hipStream_t stream)
{
    const int* left_x      = (const int*)d_in[0];
    const int* right_x     = (const int*)d_in[2];
    const int* left_batch  = (const int*)d_in[4];
    const int* right_batch = (const int*)d_in[5];
    const int* anc_d  = (const int*)d_in[8];
    const int* leaf_d = (const int*)d_in[9];
    const int* anc_p  = (const int*)d_in[10];
    const int* leaf_p = (const int*)d_in[11];
    const int* anc_a  = (const int*)d_in[12];
    const int* leaf_a = (const int*)d_in[13];
    const float* emb_d = (const float*)d_in[14];
    const float* emb_p = (const float*)d_in[15];
    const float* emb_a = (const float*)d_in[16];
    const float* Wl_d = (const float*)d_in[17];
    const float* bl_d = (const float*)d_in[18];
    const float* ap_d = (const float*)d_in[19];
    const float* Wl_p = (const float*)d_in[20];
    const float* bl_p = (const float*)d_in[21];
    const float* ap_p = (const float*)d_in[22];
    const float* Wl_a = (const float*)d_in[23];
    const float* bl_a = (const float*)d_in[24];
    const float* ap_a = (const float*)d_in[25];
    const float* W_ntn = (const float*)d_in[26];
    const float* V_ntn = (const float*)d_in[27];
    const float* b_ntn = (const float*)d_in[28];
    const float* w_fc  = (const float*)d_in[29];
    const float* b_fc  = (const float*)d_in[30];
    float* out = (float*)d_out;

    float* ws = (float*)d_ws;
    float* s_sum   = ws;                                    // 64 floats (13 used)
    float* le      = ws + 64;                               // 4096*128
    float* re      = le + (size_t)BB * HID;                 // 4096*128
    float* all_emb = re + (size_t)BB * HID;                 // 18000*128
    float* part    = all_emb + (size_t)(VD + VP + VA) * HID;// 8*4096*16
    bf16*  U       = (bf16*)(part + (size_t)8 * BB * PD);   // 23400*256 bf16
    bf16*  U_d = U;
    bf16*  U_p = U_d + (size_t)NGD * 256;
    bf16*  U_a = U_p + (size_t)NGP * 256;
    bf16*  B3_d = U_a + (size_t)NGA * 256;                  // 3 * 32768 bf16
    bf16*  B3_p = B3_d + 32768;
    bf16*  B3_a = B3_p + 32768;

    prep_b3<<<48, 256, 0, stream>>>(Wl_d, Wl_p, Wl_a, B3_d, B3_p, B3_a);

    hipMemsetAsync(s_sum, 0, 16 * sizeof(float), stream);

    stage1_mfma<<<NB_D + NB_P + NB_A, 256, 0, stream>>>(
        emb_d, B3_d, U_d, emb_p, B3_p, U_p, emb_a, B3_a, U_a);

    aw_all<<<1024, 256, 0, stream>>>(
        U_d, anc_d, leaf_d, bl_d, ap_d,
        U_p, anc_p, leaf_p, bl_p, ap_p,
        U_a, anc_a, leaf_a, bl_a, ap_a, s_sum);

    allemb_all<<<1024, 256, 0, stream>>>(
        emb_d, anc_d, emb_p, anc_p, emb_a, anc_a, s_sum, all_emb);

    segsum_both<<<2 * BB, 256, 0, stream>>>(
        all_emb, left_x, left_batch, le, right_x, right_batch, re);

    ntn_part<<<dim3(64, 8), 256, 0, stream>>>(le, re, W_ntn, part);

    ntn_epi<<<BB / 16, 256, 0, stream>>>(part, le, re, V_ntn, b_ntn, w_fc, b_fc, out);
}

// Round 5
// 245.791 us; speedup vs baseline: 2.1749x; 1.1003x over previous
//
#include <hip/hip_runtime.h>
#include <hip/hip_bf16.h>

typedef __hip_bfloat16 bf16;
typedef __attribute__((ext_vector_type(8))) short bf16x8;
typedef __attribute__((ext_vector_type(4))) float f32x4;

#define HID 128
#define PD  16
#define BB  4096
#define TT  262144
#define VD  10000
#define VP  4000
#define VA  4000
#define NGD 13000
#define NGP 5200
#define NGA 5200

#define NB_D ((NGD + 31) / 32)   // 407
#define NB_P ((NGP + 31) / 32)   // 163
#define NB_A ((NGA + 31) / 32)   // 163

__device__ __forceinline__ float2 bf2x(unsigned int u) {
    float lo = __uint_as_float(u << 16);
    float hi = __uint_as_float(u & 0xffff0000u);
    return make_float2(lo, hi);
}

union Pack2 { bf16 h[2]; unsigned int u; };
__device__ __forceinline__ unsigned int pk2(float a, float b) {
    Pack2 p; p.h[0] = __float2bfloat16(a); p.h[1] = __float2bfloat16(b); return p.u;
}

// ---------------- K0: prep W fragments (fragment-major bf16 for MFMA A-operand)
__global__ __launch_bounds__(256) void prep_b3(
    const float* __restrict__ Wl_d, const float* __restrict__ Wl_p, const float* __restrict__ Wl_a,
    bf16* __restrict__ B3_d, bf16* __restrict__ B3_p, bf16* __restrict__ B3_a)
{
    const int sec = blockIdx.x >> 4, jt = blockIdx.x & 15;
    const float* Wl = (sec == 0) ? Wl_d : (sec == 1) ? Wl_p : Wl_a;
    bf16* B3 = (sec == 0) ? B3_d : (sec == 1) ? B3_p : B3_a;
    const int tid = threadIdx.x;
    const int q = tid >> 6, lane = tid & 63;
    const int quad = lane >> 4, m = lane & 15;
    const int col = jt * 16 + m;
    const float* src = (col < 128) ? (Wl + col * 256) : (Wl + (col - 128) * 256 + 128);
    unsigned int pk[4];
#pragma unroll
    for (int jp = 0; jp < 4; ++jp) {
        int k0 = q * 32 + quad * 8 + 2 * jp;
        pk[jp] = pk2(src[k0], src[k0 + 1]);
    }
    uint4 val = make_uint4(pk[0], pk[1], pk[2], pk[3]);
    *reinterpret_cast<uint4*>(B3 + ((size_t)(jt * 4 + q) * 64 + lane) * 8) = val;
}

// ---------------- K1: U[g, 0..255] via bf16 MFMA
__device__ __forceinline__ void stage1_body(
    unsigned short (*Abf)[136],
    const float* __restrict__ emb, const bf16* __restrict__ B3,
    bf16* __restrict__ U, int NG, int blk)
{
    const int tid  = threadIdx.x;
    const int row0 = blk * 32;
    {
        const int r = tid >> 3, seg = tid & 7;
        const int g = row0 + r;
        float v[16];
        if (g < NG) {
            const float4* src = reinterpret_cast<const float4*>(emb + (size_t)g * HID + seg * 16);
#pragma unroll
            for (int i = 0; i < 4; ++i) {
                float4 f = src[i];
                v[4 * i] = f.x; v[4 * i + 1] = f.y; v[4 * i + 2] = f.z; v[4 * i + 3] = f.w;
            }
        } else {
#pragma unroll
            for (int i = 0; i < 16; ++i) v[i] = 0.f;
        }
        unsigned int pk[8];
#pragma unroll
        for (int i = 0; i < 8; ++i) pk[i] = pk2(v[2 * i], v[2 * i + 1]);
        uint4* dst = reinterpret_cast<uint4*>(&Abf[r][seg * 16]);
        dst[0] = make_uint4(pk[0], pk[1], pk[2], pk[3]);
        dst[1] = make_uint4(pk[4], pk[5], pk[6], pk[7]);
    }
    __syncthreads();

    const int lane   = tid & 63;
    const int w      = tid >> 6;
    const int gtile  = w & 1;
    const int jstrip = w >> 1;
    const int lrow   = gtile * 16 + (lane & 15);
    const int koff   = (lane >> 4) * 8;
    const bf16x8* B3f = reinterpret_cast<const bf16x8*>(B3);

    f32x4 acc[8];
#pragma unroll
    for (int t = 0; t < 8; ++t) acc[t] = (f32x4){0.f, 0.f, 0.f, 0.f};

#pragma unroll
    for (int q = 0; q < 4; ++q) {
        bf16x8 ef = *reinterpret_cast<const bf16x8*>(&Abf[lrow][q * 32 + koff]);
#pragma unroll
        for (int t = 0; t < 8; ++t) {
            int jt = jstrip * 8 + t;
            bf16x8 wf = B3f[(jt * 4 + q) * 64 + lane];
            acc[t] = __builtin_amdgcn_mfma_f32_16x16x32_bf16(wf, ef, acc[t], 0, 0, 0);
        }
    }

    const int g = row0 + gtile * 16 + (lane & 15);
    if (g < NG) {
        const int quad = lane >> 4;
        bf16* Ur = U + (size_t)g * 256;
#pragma unroll
        for (int t = 0; t < 8; ++t) {
            int j0 = (jstrip * 8 + t) * 16 + quad * 4;
            uint2 st = make_uint2(pk2(acc[t].x, acc[t].y), pk2(acc[t].z, acc[t].w));
            *reinterpret_cast<uint2*>(Ur + j0) = st;
        }
    }
}

__global__ __launch_bounds__(256) void stage1_mfma(
    const float* __restrict__ emb_d, const bf16* __restrict__ B3_d, bf16* __restrict__ U_d,
    const float* __restrict__ emb_p, const bf16* __restrict__ B3_p, bf16* __restrict__ U_p,
    const float* __restrict__ emb_a, const bf16* __restrict__ B3_a, bf16* __restrict__ U_a)
{
    __shared__ unsigned short Abf[32][136];
    int bx = blockIdx.x;
    if (bx < NB_D)             stage1_body(Abf, emb_d, B3_d, U_d, NGD, bx);
    else if (bx < NB_D + NB_P) stage1_body(Abf, emb_p, B3_p, U_p, NGP, bx - NB_D);
    else                       stage1_body(Abf, emb_a, B3_a, U_a, NGA, bx - NB_D - NB_P);
}

// ---------------- K2: aw + softmax + global s_sum
template <int L>
__device__ __forceinline__ void aw_body(
    float* sacc,
    const bf16* __restrict__ U, const int* __restrict__ anc, const int* __restrict__ leaf,
    const float* __restrict__ bl, const float* __restrict__ ap,
    float* __restrict__ s_out, int V, int blk, int nblk)
{
    const int tid  = threadIdx.x;
    const int lane = tid & 63;
    const int wid  = blk * 4 + (tid >> 6);
    const int nw   = nblk * 4;
    const float2 blv = *reinterpret_cast<const float2*>(bl + 2 * lane);
    const float2 apv = *reinterpret_cast<const float2*>(ap + 2 * lane);
    const unsigned int* Uw = reinterpret_cast<const unsigned int*>(U);
    float wacc[L];
#pragma unroll
    for (int l = 0; l < L; ++l) wacc[l] = 0.f;

    for (int v = wid; v < V; v += nw) {
        float aw[L];
#pragma unroll
        for (int l = 0; l < L; ++l) {
            int a = anc[v * L + l];
            int f = leaf[v * L + l];
            float2 a2 = bf2x(Uw[(size_t)a * 128 + lane]);
            float2 l2 = bf2x(Uw[(size_t)f * 128 + 64 + lane]);
            float t0 = tanhf(a2.x + l2.x + blv.x);
            float t1 = tanhf(a2.y + l2.y + blv.y);
            float p = t0 * apv.x + t1 * apv.y;
#pragma unroll
            for (int off = 32; off; off >>= 1) p += __shfl_xor(p, off, 64);
            aw[l] = p;
        }
        float m = aw[0];
#pragma unroll
        for (int l = 1; l < L; ++l) m = fmaxf(m, aw[l]);
        float den = 0.f, e[L];
#pragma unroll
        for (int l = 0; l < L; ++l) { e[l] = __expf(aw[l] - m); den += e[l]; }
        float inv = 1.f / den;
#pragma unroll
        for (int l = 0; l < L; ++l) wacc[l] += e[l] * inv;
    }
    if (lane == 0) {
#pragma unroll
        for (int l = 0; l < L; ++l) atomicAdd(&sacc[l], wacc[l]);
    }
    __syncthreads();
    if (tid < L) atomicAdd(&s_out[tid], sacc[tid]);
}

__global__ __launch_bounds__(256) void aw_all(
    const bf16* __restrict__ U_d, const int* __restrict__ anc_d, const int* __restrict__ leaf_d,
    const float* __restrict__ bl_d, const float* __restrict__ ap_d,
    const bf16* __restrict__ U_p, const int* __restrict__ anc_p, const int* __restrict__ leaf_p,
    const float* __restrict__ bl_p, const float* __restrict__ ap_p,
    const bf16* __restrict__ U_a, const int* __restrict__ anc_a, const int* __restrict__ leaf_a,
    const float* __restrict__ bl_a, const float* __restrict__ ap_a,
    float* __restrict__ s_sum)
{
    __shared__ float sacc[5];
    const int tid = threadIdx.x;
    if (tid < 5) sacc[tid] = 0.f;
    __syncthreads();
    int bx = blockIdx.x;
    if (bx < 512)      aw_body<4>(sacc, U_d, anc_d, leaf_d, bl_d, ap_d, s_sum + 0, VD, bx, 512);
    else if (bx < 768) aw_body<4>(sacc, U_p, anc_p, leaf_p, bl_p, ap_p, s_sum + 4, VP, bx - 512, 256);
    else               aw_body<5>(sacc, U_a, anc_a, leaf_a, bl_a, ap_a, s_sum + 8, VA, bx - 768, 256);
}

// ---------------- K3: all_emb[v,:] = sum_l s[l] * emb[anc[v,l],:]  (float4 gather)
template <int L>
__device__ __forceinline__ void allemb_body(
    const float* __restrict__ emb, const int* __restrict__ anc,
    const float* __restrict__ s, float* __restrict__ out, int V, int blk, int nblk)
{
    const int tid   = threadIdx.x;
    const int lane4 = tid & 31;
    const int vslot = tid >> 5;
    const float4* emb4 = reinterpret_cast<const float4*>(emb);
    float4* out4 = reinterpret_cast<float4*>(out);
    float sv[L];
#pragma unroll
    for (int l = 0; l < L; ++l) sv[l] = s[l];
    for (int v = blk * 8 + vslot; v < V; v += nblk * 8) {
        float4 a = make_float4(0.f, 0.f, 0.f, 0.f);
#pragma unroll
        for (int l = 0; l < L; ++l) {
            float4 e = emb4[(size_t)anc[v * L + l] * 32 + lane4];
            a.x += sv[l] * e.x; a.y += sv[l] * e.y;
            a.z += sv[l] * e.z; a.w += sv[l] * e.w;
        }
        out4[(size_t)v * 32 + lane4] = a;
    }
}

__global__ __launch_bounds__(256) void allemb_all(
    const float* __restrict__ emb_d, const int* __restrict__ anc_d,
    const float* __restrict__ emb_p, const int* __restrict__ anc_p,
    const float* __restrict__ emb_a, const int* __restrict__ anc_a,
    const float* __restrict__ s_sum, float* __restrict__ all_emb)
{
    int bx = blockIdx.x;
    if (bx < 512)
        allemb_body<4>(emb_d, anc_d, s_sum + 0, all_emb, VD, bx, 512);
    else if (bx < 768)
        allemb_body<4>(emb_p, anc_p, s_sum + 4, all_emb + (size_t)VD * HID, VP, bx - 512, 256);
    else
        allemb_body<5>(emb_a, anc_a, s_sum + 8, all_emb + (size_t)(VD + VP) * HID, VA, bx - 768, 256);
}

// ---------------- K4a: precompute segment bounds (lower_bound of each b)
__global__ __launch_bounds__(256) void seg_bounds(
    const int* __restrict__ lb, const int* __restrict__ rb,
    int* __restrict__ segL, int* __restrict__ segR)
{
    int gid = blockIdx.x * 256 + threadIdx.x;
    const int* batch;
    int* segp;
    int b;
    if (gid <= BB) { batch = lb; segp = segL; b = gid; }
    else if (gid <= 2 * BB + 1) { batch = rb; segp = segR; b = gid - BB - 1; }
    else return;
    int l = 0, r = TT;
    while (l < r) { int m = (l + r) >> 1; if (batch[m] < b) l = m + 1; else r = m; }
    segp[b] = l;
}

// ---------------- K4b: segment sum, float4 gathers, 8 rows in flight, LDS reduce
__global__ __launch_bounds__(256) void segsum_f4(
    const float* __restrict__ all_emb,
    const int* __restrict__ lx, const int* __restrict__ segL, float* __restrict__ le,
    const int* __restrict__ rx, const int* __restrict__ segR, float* __restrict__ re)
{
    __shared__ float4 red[8][32];
    const int tid = threadIdx.x;
    const int b   = blockIdx.x & (BB - 1);
    const int* x;
    const int* seg;
    float* out;
    if (blockIdx.x < BB) { x = lx; seg = segL; out = le; }
    else                 { x = rx; seg = segR; out = re; }
    const int lo = seg[b], hi = seg[b + 1];
    const int lane4 = tid & 31;
    const int slot  = tid >> 5;
    const float4* AE4 = reinterpret_cast<const float4*>(all_emb);
    float4 acc = make_float4(0.f, 0.f, 0.f, 0.f);
    int t = lo + slot;
    for (; t + 8 < hi; t += 16) {
        int i0 = x[t], i1 = x[t + 8];
        float4 v0 = AE4[(size_t)i0 * 32 + lane4];
        float4 v1 = AE4[(size_t)i1 * 32 + lane4];
        acc.x += v0.x; acc.y += v0.y; acc.z += v0.z; acc.w += v0.w;
        acc.x += v1.x; acc.y += v1.y; acc.z += v1.z; acc.w += v1.w;
    }
    for (; t < hi; t += 8) {
        float4 v0 = AE4[(size_t)x[t] * 32 + lane4];
        acc.x += v0.x; acc.y += v0.y; acc.z += v0.z; acc.w += v0.w;
    }
    red[slot][lane4] = acc;
    __syncthreads();
    if (slot < 4) {
        float4 o = red[slot + 4][lane4];
        acc.x += o.x; acc.y += o.y; acc.z += o.z; acc.w += o.w;
        red[slot][lane4] = acc;
    }
    __syncthreads();
    if (slot < 2) {
        float4 o = red[slot + 2][lane4];
        acc.x += o.x; acc.y += o.y; acc.z += o.z; acc.w += o.w;
        red[slot][lane4] = acc;
    }
    __syncthreads();
    if (slot == 0) {
        float4 o = red[1][lane4];
        acc.x += o.x; acc.y += o.y; acc.z += o.z; acc.w += o.w;
        reinterpret_cast<float4*>(out)[(size_t)b * 32 + lane4] = acc;
    }
}

// ---------------- K5a: NTN GEMM tile + contraction with re -> partial bilinear
__global__ __launch_bounds__(256) void ntn_part(
    const float* __restrict__ le, const float* __restrict__ re,
    const float* __restrict__ W2, float* __restrict__ part)
{
    __shared__ float Alds[32][68];
    __shared__ float Blds[32 * 264];
    __shared__ float Rlds[64][17];
    const int tid   = threadIdx.x;
    const int row0  = blockIdx.x * 64;
    const int col0  = blockIdx.y * 256;
    const int lane5 = tid & 31;
    const int rbase = (tid >> 5) * 8;
    const int cbase = lane5 * 8;
    float acc[8][8];
#pragma unroll
    for (int i = 0; i < 8; ++i)
#pragma unroll
        for (int j = 0; j < 8; ++j) acc[i][j] = 0.f;

    for (int i = tid; i < 64 * 16; i += 256) {
        int rr = i >> 4, jl = i & 15;
        Rlds[rr][jl] = re[(size_t)(row0 + rr) * HID + blockIdx.y * 16 + jl];
    }

    for (int k0 = 0; k0 < 128; k0 += 32) {
        __syncthreads();
        for (int i = tid; i < 64 * 32; i += 256) {
            int rr = i >> 5, kk = i & 31;
            Alds[kk][rr] = le[(size_t)(row0 + rr) * HID + k0 + kk];
        }
        for (int i = tid; i < 32 * 64; i += 256) {
            int kk = i >> 6, j4 = (i & 63) * 4;
            float4 v = *reinterpret_cast<const float4*>(&W2[(size_t)(k0 + kk) * 2048 + col0 + j4]);
            *reinterpret_cast<float4*>(&Blds[kk * 264 + j4]) = v;
        }
        __syncthreads();
#pragma unroll
        for (int kk = 0; kk < 32; ++kk) {
            float4 a0 = *reinterpret_cast<const float4*>(&Alds[kk][rbase]);
            float4 a1 = *reinterpret_cast<const float4*>(&Alds[kk][rbase + 4]);
            float4 b0 = *reinterpret_cast<const float4*>(&Blds[kk * 264 + cbase]);
            float4 b1 = *reinterpret_cast<const float4*>(&Blds[kk * 264 + cbase + 4]);
            float av[8] = {a0.x, a0.y, a0.z, a0.w, a1.x, a1.y, a1.z, a1.w};
            float bv[8] = {b0.x, b0.y, b0.z, b0.w, b1.x, b1.y, b1.z, b1.w};
#pragma unroll
            for (int i = 0; i < 8; ++i)
#pragma unroll
                for (int j = 0; j < 8; ++j) acc[i][j] += av[i] * bv[j];
        }
    }

    const int jloc = lane5 >> 1;
    const int pq   = (tid & 1) * 8;
#pragma unroll
    for (int i = 0; i < 8; ++i) {
        int row = rbase + i;
        float rj = Rlds[row][jloc];
        float pb[8];
#pragma unroll
        for (int j = 0; j < 8; ++j) pb[j] = acc[i][j] * rj;
#pragma unroll
        for (int m = 2; m <= 16; m <<= 1) {
#pragma unroll
            for (int j = 0; j < 8; ++j) pb[j] += __shfl_xor(pb[j], m, 64);
        }
        if ((tid & 30) == 0) {
            size_t base = ((size_t)blockIdx.y * BB + row0 + row) * PD + pq;
            *reinterpret_cast<float4*>(&part[base])     = make_float4(pb[0], pb[1], pb[2], pb[3]);
            *reinterpret_cast<float4*>(&part[base + 4]) = make_float4(pb[4], pb[5], pb[6], pb[7]);
        }
    }
}

// ---------------- K5b: sum partials + block term + tanh + fc + sigmoid
__global__ __launch_bounds__(256) void ntn_epi(
    const float* __restrict__ part, const float* __restrict__ le, const float* __restrict__ re,
    const float* __restrict__ Vntn, const float* __restrict__ bntn,
    const float* __restrict__ wfc, const float* __restrict__ bfc,
    float* __restrict__ out)
{
    __shared__ float Vlds[16 * 257];
    __shared__ float LE[16 * 128];
    __shared__ float RE[16 * 128];
    const int tid = threadIdx.x;
    const int b0  = blockIdx.x * 16;
    for (int i = tid; i < 4096; i += 256) Vlds[(i >> 8) * 257 + (i & 255)] = Vntn[i];
    for (int i = tid; i < 2048; i += 256) {
        LE[i] = le[(size_t)b0 * HID + i];
        RE[i] = re[(size_t)b0 * HID + i];
    }
    __syncthreads();
    const int bl = tid >> 4, p = tid & 15;
    const int b  = b0 + bl;
    float bil = 0.f;
#pragma unroll
    for (int by = 0; by < 8; ++by) bil += part[((size_t)by * BB + b) * PD + p];
    float s = bil + bntn[p];
    const float* Vp   = &Vlds[p * 257];
    const float* lrow = &LE[bl * 128];
    const float* rrow = &RE[bl * 128];
#pragma unroll 8
    for (int c = 0; c < 128; ++c) s += lrow[c] * Vp[c] + rrow[c] * Vp[128 + c];
    float x = tanhf(s) * wfc[p];
    x += __shfl_xor(x, 1, 64);
    x += __shfl_xor(x, 2, 64);
    x += __shfl_xor(x, 4, 64);
    x += __shfl_xor(x, 8, 64);
    if (p == 0) out[b] = 1.f / (1.f + __expf(-(x + bfc[0])));
}

extern "C" void kernel_launch(void* const* d_in, const int* in_sizes, int n_in,
                              void* d_out, int out_size, void* d_ws, size_t ws_size,
                              hipStream_t stream)
{
    const int* left_x      = (const int*)d_in[0];
    const int* right_x     = (const int*)d_in[2];
    const int* left_batch  = (const int*)d_in[4];
    const int* right_batch = (const int*)d_in[5];
    const int* anc_d  = (const int*)d_in[8];
    const int* leaf_d = (const int*)d_in[9];
    const int* anc_p  = (const int*)d_in[10];
    const int* leaf_p = (const int*)d_in[11];
    const int* anc_a  = (const int*)d_in[12];
    const int* leaf_a = (const int*)d_in[13];
    const float* emb_d = (const float*)d_in[14];
    const float* emb_p = (const float*)d_in[15];
    const float* emb_a = (const float*)d_in[16];
    const float* Wl_d = (const float*)d_in[17];
    const float* bl_d = (const float*)d_in[18];
    const float* ap_d = (const float*)d_in[19];
    const float* Wl_p = (const float*)d_in[20];
    const float* bl_p = (const float*)d_in[21];
    const float* ap_p = (const float*)d_in[22];
    const float* Wl_a = (const float*)d_in[23];
    const float* bl_a = (const float*)d_in[24];
    const float* ap_a = (const float*)d_in[25];
    const float* W_ntn = (const float*)d_in[26];
    const float* V_ntn = (const float*)d_in[27];
    const float* b_ntn = (const float*)d_in[28];
    const float* w_fc  = (const float*)d_in[29];
    const float* b_fc  = (const float*)d_in[30];
    float* out = (float*)d_out;

    float* ws = (float*)d_ws;
    float* s_sum   = ws;                                    // 64 floats (13 used)
    float* le      = ws + 64;                               // 4096*128
    float* re      = le + (size_t)BB * HID;                 // 4096*128
    float* all_emb = re + (size_t)BB * HID;                 // 18000*128
    float* part    = all_emb + (size_t)(VD + VP + VA) * HID;// 8*4096*16
    int*   segL    = (int*)(part + (size_t)8 * BB * PD);    // 4100
    int*   segR    = segL + 4100;                           // 4100
    bf16*  U       = (bf16*)(segR + 4100);                  // 23400*256 bf16
    bf16*  U_d = U;
    bf16*  U_p = U_d + (size_t)NGD * 256;
    bf16*  U_a = U_p + (size_t)NGP * 256;
    bf16*  B3_d = U_a + (size_t)NGA * 256;                  // 3 * 32768 bf16
    bf16*  B3_p = B3_d + 32768;
    bf16*  B3_a = B3_p + 32768;

    prep_b3<<<48, 256, 0, stream>>>(Wl_d, Wl_p, Wl_a, B3_d, B3_p, B3_a);

    hipMemsetAsync(s_sum, 0, 16 * sizeof(float), stream);

    seg_bounds<<<33, 256, 0, stream>>>(left_batch, right_batch, segL, segR);

    stage1_mfma<<<NB_D + NB_P + NB_A, 256, 0, stream>>>(
        emb_d, B3_d, U_d, emb_p, B3_p, U_p, emb_a, B3_a, U_a);

    aw_all<<<1024, 256, 0, stream>>>(
        U_d, anc_d, leaf_d, bl_d, ap_d,
        U_p, anc_p, leaf_p, bl_p, ap_p,
        U_a, anc_a, leaf_a, bl_a, ap_a, s_sum);

    allemb_all<<<1024, 256, 0, stream>>>(
        emb_d, anc_d, emb_p, anc_p, emb_a, anc_a, s_sum, all_emb);

    segsum_f4<<<2 * BB, 256, 0, stream>>>(
        all_emb, left_x, segL, le, right_x, segR, re);

    ntn_part<<<dim3(64, 8), 256, 0, stream>>>(le, re, W_ntn, part);

    ntn_epi<<<BB / 16, 256, 0, stream>>>(part, le, re, V_ntn, b_ntn, w_fc, b_fc, out);
}

// Round 6
// 238.098 us; speedup vs baseline: 2.2452x; 1.0323x over previous
//
#include <hip/hip_runtime.h>
#include <hip/hip_bf16.h>

typedef __hip_bfloat16 bf16;
typedef __attribute__((ext_vector_type(8))) short bf16x8;
typedef __attribute__((ext_vector_type(4))) float f32x4;

#define HID 128
#define PD  16
#define BB  4096
#define TT  262144
#define VD  10000
#define VP  4000
#define VA  4000
#define NGD 13000
#define NGP 5200
#define NGA 5200

#define NB_D ((NGD + 31) / 32)   // 407
#define NB_P ((NGP + 31) / 32)   // 163
#define NB_A ((NGA + 31) / 32)   // 163

__device__ __forceinline__ float2 bf2x(unsigned int u) {
    float lo = __uint_as_float(u << 16);
    float hi = __uint_as_float(u & 0xffff0000u);
    return make_float2(lo, hi);
}

union Pack2 { bf16 h[2]; unsigned int u; };
__device__ __forceinline__ unsigned int pk2(float a, float b) {
    Pack2 p; p.h[0] = __float2bfloat16(a); p.h[1] = __float2bfloat16(b); return p.u;
}

// ---------------- K0: prep W fragments (fragment-major bf16 for MFMA A-operand)
__global__ __launch_bounds__(256) void prep_b3(
    const float* __restrict__ Wl_d, const float* __restrict__ Wl_p, const float* __restrict__ Wl_a,
    bf16* __restrict__ B3_d, bf16* __restrict__ B3_p, bf16* __restrict__ B3_a)
{
    const int sec = blockIdx.x >> 4, jt = blockIdx.x & 15;
    const float* Wl = (sec == 0) ? Wl_d : (sec == 1) ? Wl_p : Wl_a;
    bf16* B3 = (sec == 0) ? B3_d : (sec == 1) ? B3_p : B3_a;
    const int tid = threadIdx.x;
    const int q = tid >> 6, lane = tid & 63;
    const int quad = lane >> 4, m = lane & 15;
    const int col = jt * 16 + m;
    const float* src = (col < 128) ? (Wl + col * 256) : (Wl + (col - 128) * 256 + 128);
    unsigned int pk[4];
#pragma unroll
    for (int jp = 0; jp < 4; ++jp) {
        int k0 = q * 32 + quad * 8 + 2 * jp;
        pk[jp] = pk2(src[k0], src[k0 + 1]);
    }
    uint4 val = make_uint4(pk[0], pk[1], pk[2], pk[3]);
    *reinterpret_cast<uint4*>(B3 + ((size_t)(jt * 4 + q) * 64 + lane) * 8) = val;
}

// ---------------- K1: U[g, 0..255] via bf16 MFMA
__device__ __forceinline__ void stage1_body(
    unsigned short (*Abf)[136],
    const float* __restrict__ emb, const bf16* __restrict__ B3,
    bf16* __restrict__ U, int NG, int blk)
{
    const int tid  = threadIdx.x;
    const int row0 = blk * 32;
    {
        const int r = tid >> 3, seg = tid & 7;
        const int g = row0 + r;
        float v[16];
        if (g < NG) {
            const float4* src = reinterpret_cast<const float4*>(emb + (size_t)g * HID + seg * 16);
#pragma unroll
            for (int i = 0; i < 4; ++i) {
                float4 f = src[i];
                v[4 * i] = f.x; v[4 * i + 1] = f.y; v[4 * i + 2] = f.z; v[4 * i + 3] = f.w;
            }
        } else {
#pragma unroll
            for (int i = 0; i < 16; ++i) v[i] = 0.f;
        }
        unsigned int pk[8];
#pragma unroll
        for (int i = 0; i < 8; ++i) pk[i] = pk2(v[2 * i], v[2 * i + 1]);
        uint4* dst = reinterpret_cast<uint4*>(&Abf[r][seg * 16]);
        dst[0] = make_uint4(pk[0], pk[1], pk[2], pk[3]);
        dst[1] = make_uint4(pk[4], pk[5], pk[6], pk[7]);
    }
    __syncthreads();

    const int lane   = tid & 63;
    const int w      = tid >> 6;
    const int gtile  = w & 1;
    const int jstrip = w >> 1;
    const int lrow   = gtile * 16 + (lane & 15);
    const int koff   = (lane >> 4) * 8;
    const bf16x8* B3f = reinterpret_cast<const bf16x8*>(B3);

    f32x4 acc[8];
#pragma unroll
    for (int t = 0; t < 8; ++t) acc[t] = (f32x4){0.f, 0.f, 0.f, 0.f};

#pragma unroll
    for (int q = 0; q < 4; ++q) {
        bf16x8 ef = *reinterpret_cast<const bf16x8*>(&Abf[lrow][q * 32 + koff]);
#pragma unroll
        for (int t = 0; t < 8; ++t) {
            int jt = jstrip * 8 + t;
            bf16x8 wf = B3f[(jt * 4 + q) * 64 + lane];
            acc[t] = __builtin_amdgcn_mfma_f32_16x16x32_bf16(wf, ef, acc[t], 0, 0, 0);
        }
    }

    const int g = row0 + gtile * 16 + (lane & 15);
    if (g < NG) {
        const int quad = lane >> 4;
        bf16* Ur = U + (size_t)g * 256;
#pragma unroll
        for (int t = 0; t < 8; ++t) {
            int j0 = (jstrip * 8 + t) * 16 + quad * 4;
            uint2 st = make_uint2(pk2(acc[t].x, acc[t].y), pk2(acc[t].z, acc[t].w));
            *reinterpret_cast<uint2*>(Ur + j0) = st;
        }
    }
}

__global__ __launch_bounds__(256) void stage1_mfma(
    const float* __restrict__ emb_d, const bf16* __restrict__ B3_d, bf16* __restrict__ U_d,
    const float* __restrict__ emb_p, const bf16* __restrict__ B3_p, bf16* __restrict__ U_p,
    const float* __restrict__ emb_a, const bf16* __restrict__ B3_a, bf16* __restrict__ U_a)
{
    __shared__ unsigned short Abf[32][136];
    int bx = blockIdx.x;
    if (bx < NB_D)             stage1_body(Abf, emb_d, B3_d, U_d, NGD, bx);
    else if (bx < NB_D + NB_P) stage1_body(Abf, emb_p, B3_p, U_p, NGP, bx - NB_D);
    else                       stage1_body(Abf, emb_a, B3_a, U_a, NGA, bx - NB_D - NB_P);
}

// ---------------- K2: aw + softmax + global s_sum  (2 vertices per iteration)
template <int L>
__device__ __forceinline__ void aw_body(
    float* sacc,
    const bf16* __restrict__ U, const int* __restrict__ anc, const int* __restrict__ leaf,
    const float* __restrict__ bl, const float* __restrict__ ap,
    float* __restrict__ s_out, int V, int blk, int nblk)
{
    const int tid  = threadIdx.x;
    const int lane = tid & 63;
    const int wid  = blk * 4 + (tid >> 6);
    const int nw   = nblk * 4;
    const float2 blv = *reinterpret_cast<const float2*>(bl + 2 * lane);
    const float2 apv = *reinterpret_cast<const float2*>(ap + 2 * lane);
    const unsigned int* Uw = reinterpret_cast<const unsigned int*>(U);
    float wacc[L];
#pragma unroll
    for (int l = 0; l < L; ++l) wacc[l] = 0.f;

    for (int vp = wid; vp < V / 2; vp += nw) {
        const int v0 = 2 * vp;
        int a0[L], f0[L], a1[L], f1[L];
        if (L == 4) {
            int4 ia = *reinterpret_cast<const int4*>(anc  + (size_t)v0 * 4);
            int4 ib = *reinterpret_cast<const int4*>(anc  + (size_t)v0 * 4 + 4);
            int4 fa = *reinterpret_cast<const int4*>(leaf + (size_t)v0 * 4);
            int4 fb = *reinterpret_cast<const int4*>(leaf + (size_t)v0 * 4 + 4);
            a0[0] = ia.x; a0[1] = ia.y; a0[2] = ia.z; a0[3] = ia.w;
            a1[0] = ib.x; a1[1] = ib.y; a1[2] = ib.z; a1[3] = ib.w;
            f0[0] = fa.x; f0[1] = fa.y; f0[2] = fa.z; f0[3] = fa.w;
            f1[0] = fb.x; f1[1] = fb.y; f1[2] = fb.z; f1[3] = fb.w;
        } else {
#pragma unroll
            for (int l = 0; l < L; ++l) {
                a0[l] = anc[(size_t)v0 * L + l];
                a1[l] = anc[(size_t)(v0 + 1) * L + l];
                f0[l] = leaf[(size_t)v0 * L + l];
                f1[l] = leaf[(size_t)(v0 + 1) * L + l];
            }
        }
        unsigned int ua0[L], ul0[L], ua1[L], ul1[L];
#pragma unroll
        for (int l = 0; l < L; ++l) {
            ua0[l] = Uw[(size_t)a0[l] * 128 + lane];
            ul0[l] = Uw[(size_t)f0[l] * 128 + 64 + lane];
            ua1[l] = Uw[(size_t)a1[l] * 128 + lane];
            ul1[l] = Uw[(size_t)f1[l] * 128 + 64 + lane];
        }
        float aw0[L], aw1[L];
#pragma unroll
        for (int l = 0; l < L; ++l) {
            float2 x0 = bf2x(ua0[l]), y0 = bf2x(ul0[l]);
            float2 x1 = bf2x(ua1[l]), y1 = bf2x(ul1[l]);
            float p0 = tanhf(x0.x + y0.x + blv.x) * apv.x + tanhf(x0.y + y0.y + blv.y) * apv.y;
            float p1 = tanhf(x1.x + y1.x + blv.x) * apv.x + tanhf(x1.y + y1.y + blv.y) * apv.y;
#pragma unroll
            for (int off = 32; off; off >>= 1) {
                p0 += __shfl_xor(p0, off, 64);
                p1 += __shfl_xor(p1, off, 64);
            }
            aw0[l] = p0; aw1[l] = p1;
        }
        float m0 = aw0[0], m1 = aw1[0];
#pragma unroll
        for (int l = 1; l < L; ++l) { m0 = fmaxf(m0, aw0[l]); m1 = fmaxf(m1, aw1[l]); }
        float d0 = 0.f, d1 = 0.f, e0[L], e1[L];
#pragma unroll
        for (int l = 0; l < L; ++l) {
            e0[l] = __expf(aw0[l] - m0); d0 += e0[l];
            e1[l] = __expf(aw1[l] - m1); d1 += e1[l];
        }
        float i0 = 1.f / d0, i1 = 1.f / d1;
#pragma unroll
        for (int l = 0; l < L; ++l) wacc[l] += e0[l] * i0 + e1[l] * i1;
    }
    if (lane == 0) {
#pragma unroll
        for (int l = 0; l < L; ++l) atomicAdd(&sacc[l], wacc[l]);
    }
    __syncthreads();
    if (tid < L) atomicAdd(&s_out[tid], sacc[tid]);
}

__global__ __launch_bounds__(256) void aw_all(
    const bf16* __restrict__ U_d, const int* __restrict__ anc_d, const int* __restrict__ leaf_d,
    const float* __restrict__ bl_d, const float* __restrict__ ap_d,
    const bf16* __restrict__ U_p, const int* __restrict__ anc_p, const int* __restrict__ leaf_p,
    const float* __restrict__ bl_p, const float* __restrict__ ap_p,
    const bf16* __restrict__ U_a, const int* __restrict__ anc_a, const int* __restrict__ leaf_a,
    const float* __restrict__ bl_a, const float* __restrict__ ap_a,
    float* __restrict__ s_sum)
{
    __shared__ float sacc[5];
    const int tid = threadIdx.x;
    if (tid < 5) sacc[tid] = 0.f;
    __syncthreads();
    int bx = blockIdx.x;
    if (bx < 512)      aw_body<4>(sacc, U_d, anc_d, leaf_d, bl_d, ap_d, s_sum + 0, VD, bx, 512);
    else if (bx < 768) aw_body<4>(sacc, U_p, anc_p, leaf_p, bl_p, ap_p, s_sum + 4, VP, bx - 512, 256);
    else               aw_body<5>(sacc, U_a, anc_a, leaf_a, bl_a, ap_a, s_sum + 8, VA, bx - 768, 256);
}

// ---------------- K3: all_emb (float4 gathers, 2 vertices per iteration)
template <int L>
__device__ __forceinline__ void allemb_body(
    const float* __restrict__ emb, const int* __restrict__ anc,
    const float* __restrict__ s, float* __restrict__ out, int V, int blk, int nblk)
{
    const int tid   = threadIdx.x;
    const int lane4 = tid & 31;
    const int vslot = tid >> 5;
    const float4* emb4 = reinterpret_cast<const float4*>(emb);
    float4* out4 = reinterpret_cast<float4*>(out);
    float sv[L];
#pragma unroll
    for (int l = 0; l < L; ++l) sv[l] = s[l];
    for (int vp = blk * 8 + vslot; vp < V / 2; vp += nblk * 8) {
        const int v0 = 2 * vp;
        int a0[L], a1[L];
        if (L == 4) {
            int4 ia = *reinterpret_cast<const int4*>(anc + (size_t)v0 * 4);
            int4 ib = *reinterpret_cast<const int4*>(anc + (size_t)v0 * 4 + 4);
            a0[0] = ia.x; a0[1] = ia.y; a0[2] = ia.z; a0[3] = ia.w;
            a1[0] = ib.x; a1[1] = ib.y; a1[2] = ib.z; a1[3] = ib.w;
        } else {
#pragma unroll
            for (int l = 0; l < L; ++l) {
                a0[l] = anc[(size_t)v0 * L + l];
                a1[l] = anc[(size_t)(v0 + 1) * L + l];
            }
        }
        float4 e0[L], e1[L];
#pragma unroll
        for (int l = 0; l < L; ++l) {
            e0[l] = emb4[(size_t)a0[l] * 32 + lane4];
            e1[l] = emb4[(size_t)a1[l] * 32 + lane4];
        }
        float4 r0 = make_float4(0.f, 0.f, 0.f, 0.f);
        float4 r1 = make_float4(0.f, 0.f, 0.f, 0.f);
#pragma unroll
        for (int l = 0; l < L; ++l) {
            r0.x += sv[l] * e0[l].x; r0.y += sv[l] * e0[l].y;
            r0.z += sv[l] * e0[l].z; r0.w += sv[l] * e0[l].w;
            r1.x += sv[l] * e1[l].x; r1.y += sv[l] * e1[l].y;
            r1.z += sv[l] * e1[l].z; r1.w += sv[l] * e1[l].w;
        }
        out4[(size_t)v0 * 32 + lane4]       = r0;
        out4[(size_t)(v0 + 1) * 32 + lane4] = r1;
    }
}

__global__ __launch_bounds__(256) void allemb_all(
    const float* __restrict__ emb_d, const int* __restrict__ anc_d,
    const float* __restrict__ emb_p, const int* __restrict__ anc_p,
    const float* __restrict__ emb_a, const int* __restrict__ anc_a,
    const float* __restrict__ s_sum, float* __restrict__ all_emb)
{
    int bx = blockIdx.x;
    if (bx < 512)
        allemb_body<4>(emb_d, anc_d, s_sum + 0, all_emb, VD, bx, 512);
    else if (bx < 768)
        allemb_body<4>(emb_p, anc_p, s_sum + 4, all_emb + (size_t)VD * HID, VP, bx - 512, 256);
    else
        allemb_body<5>(emb_a, anc_a, s_sum + 8, all_emb + (size_t)(VD + VP) * HID, VA, bx - 768, 256);
}

// ---------------- K4a: segment bounds + zero s_sum (fused)
__global__ __launch_bounds__(256) void seg_bounds(
    const int* __restrict__ lb, const int* __restrict__ rb,
    int* __restrict__ segL, int* __restrict__ segR, float* __restrict__ s_sum)
{
    int gid = blockIdx.x * 256 + threadIdx.x;
    if (gid >= 2 * BB + 8 && gid < 2 * BB + 24) s_sum[gid - (2 * BB + 8)] = 0.f;
    const int* batch;
    int* segp;
    int b;
    if (gid <= BB) { batch = lb; segp = segL; b = gid; }
    else if (gid <= 2 * BB + 1) { batch = rb; segp = segR; b = gid - BB - 1; }
    else return;
    int l = 0, r = TT;
    while (l < r) { int m = (l + r) >> 1; if (batch[m] < b) l = m + 1; else r = m; }
    segp[b] = l;
}

// ---------------- K4b: segment sum — 4 waves/block, float2 row gathers, 8-deep ILP
__global__ __launch_bounds__(256) void segsum_f2(
    const float* __restrict__ all_emb,
    const int* __restrict__ lx, const int* __restrict__ segL, float* __restrict__ le,
    const int* __restrict__ rx, const int* __restrict__ segR, float* __restrict__ re)
{
    __shared__ float2 red[4][64];
    const int tid  = threadIdx.x;
    const int b    = blockIdx.x & (BB - 1);
    const int lane = tid & 63;
    const int w    = tid >> 6;
    const int* x;
    const int* seg;
    float* out;
    if (blockIdx.x < BB) { x = lx; seg = segL; out = le; }
    else                 { x = rx; seg = segR; out = re; }
    const int lo = seg[b], hi = seg[b + 1];
    const float2* AE2 = reinterpret_cast<const float2*>(all_emb);
    float2 acc = make_float2(0.f, 0.f);
    int t = lo + w;
    for (; t + 28 < hi; t += 32) {
        int idx[8];
#pragma unroll
        for (int u = 0; u < 8; ++u) idx[u] = x[t + 4 * u];
        float2 v[8];
#pragma unroll
        for (int u = 0; u < 8; ++u) v[u] = AE2[(size_t)idx[u] * 64 + lane];
#pragma unroll
        for (int u = 0; u < 8; ++u) { acc.x += v[u].x; acc.y += v[u].y; }
    }
    for (; t < hi; t += 4) {
        float2 v = AE2[(size_t)x[t] * 64 + lane];
        acc.x += v.x; acc.y += v.y;
    }
    if (w > 0) red[w][lane] = acc;
    __syncthreads();
    if (w == 0) {
        float2 r1 = red[1][lane], r2 = red[2][lane], r3 = red[3][lane];
        acc.x += r1.x + r2.x + r3.x;
        acc.y += r1.y + r2.y + r3.y;
        reinterpret_cast<float2*>(out)[(size_t)b * 64 + lane] = acc;
    }
}

// ---------------- K5a: NTN GEMM tile + contraction with re -> partial bilinear
__global__ __launch_bounds__(256) void ntn_part(
    const float* __restrict__ le, const float* __restrict__ re,
    const float* __restrict__ W2, float* __restrict__ part)
{
    __shared__ float Alds[32][68];
    __shared__ float Blds[32 * 264];
    __shared__ float Rlds[64][17];
    const int tid   = threadIdx.x;
    const int row0  = blockIdx.x * 64;
    const int col0  = blockIdx.y * 256;
    const int lane5 = tid & 31;
    const int rbase = (tid >> 5) * 8;
    const int cbase = lane5 * 8;
    float acc[8][8];
#pragma unroll
    for (int i = 0; i < 8; ++i)
#pragma unroll
        for (int j = 0; j < 8; ++j) acc[i][j] = 0.f;

    for (int i = tid; i < 64 * 16; i += 256) {
        int rr = i >> 4, jl = i & 15;
        Rlds[rr][jl] = re[(size_t)(row0 + rr) * HID + blockIdx.y * 16 + jl];
    }

    for (int k0 = 0; k0 < 128; k0 += 32) {
        __syncthreads();
        for (int i = tid; i < 64 * 32; i += 256) {
            int rr = i >> 5, kk = i & 31;
            Alds[kk][rr] = le[(size_t)(row0 + rr) * HID + k0 + kk];
        }
        for (int i = tid; i < 32 * 64; i += 256) {
            int kk = i >> 6, j4 = (i & 63) * 4;
            float4 v = *reinterpret_cast<const float4*>(&W2[(size_t)(k0 + kk) * 2048 + col0 + j4]);
            *reinterpret_cast<float4*>(&Blds[kk * 264 + j4]) = v;
        }
        __syncthreads();
#pragma unroll
        for (int kk = 0; kk < 32; ++kk) {
            float4 a0 = *reinterpret_cast<const float4*>(&Alds[kk][rbase]);
            float4 a1 = *reinterpret_cast<const float4*>(&Alds[kk][rbase + 4]);
            float4 b0 = *reinterpret_cast<const float4*>(&Blds[kk * 264 + cbase]);
            float4 b1 = *reinterpret_cast<const float4*>(&Blds[kk * 264 + cbase + 4]);
            float av[8] = {a0.x, a0.y, a0.z, a0.w, a1.x, a1.y, a1.z, a1.w};
            float bv[8] = {b0.x, b0.y, b0.z, b0.w, b1.x, b1.y, b1.z, b1.w};
#pragma unroll
            for (int i = 0; i < 8; ++i)
#pragma unroll
                for (int j = 0; j < 8; ++j) acc[i][j] += av[i] * bv[j];
        }
    }

    const int jloc = lane5 >> 1;
    const int pq   = (tid & 1) * 8;
#pragma unroll
    for (int i = 0; i < 8; ++i) {
        int row = rbase + i;
        float rj = Rlds[row][jloc];
        float pb[8];
#pragma unroll
        for (int j = 0; j < 8; ++j) pb[j] = acc[i][j] * rj;
#pragma unroll
        for (int m = 2; m <= 16; m <<= 1) {
#pragma unroll
            for (int j = 0; j < 8; ++j) pb[j] += __shfl_xor(pb[j], m, 64);
        }
        if ((tid & 30) == 0) {
            size_t base = ((size_t)blockIdx.y * BB + row0 + row) * PD + pq;
            *reinterpret_cast<float4*>(&part[base])     = make_float4(pb[0], pb[1], pb[2], pb[3]);
            *reinterpret_cast<float4*>(&part[base + 4]) = make_float4(pb[4], pb[5], pb[6], pb[7]);
        }
    }
}

// ---------------- K5b: sum partials + block term + tanh + fc + sigmoid
__global__ __launch_bounds__(256) void ntn_epi(
    const float* __restrict__ part, const float* __restrict__ le, const float* __restrict__ re,
    const float* __restrict__ Vntn, const float* __restrict__ bntn,
    const float* __restrict__ wfc, const float* __restrict__ bfc,
    float* __restrict__ out)
{
    __shared__ float Vlds[16 * 257];
    __shared__ float LE[16 * 128];
    __shared__ float RE[16 * 128];
    const int tid = threadIdx.x;
    const int b0  = blockIdx.x * 16;
    for (int i = tid; i < 4096; i += 256) Vlds[(i >> 8) * 257 + (i & 255)] = Vntn[i];
    for (int i = tid; i < 2048; i += 256) {
        LE[i] = le[(size_t)b0 * HID + i];
        RE[i] = re[(size_t)b0 * HID + i];
    }
    __syncthreads();
    const int bl = tid >> 4, p = tid & 15;
    const int b  = b0 + bl;
    float bil = 0.f;
#pragma unroll
    for (int by = 0; by < 8; ++by) bil += part[((size_t)by * BB + b) * PD + p];
    float s = bil + bntn[p];
    const float* Vp   = &Vlds[p * 257];
    const float* lrow = &LE[bl * 128];
    const float* rrow = &RE[bl * 128];
#pragma unroll 8
    for (int c = 0; c < 128; ++c) s += lrow[c] * Vp[c] + rrow[c] * Vp[128 + c];
    float x = tanhf(s) * wfc[p];
    x += __shfl_xor(x, 1, 64);
    x += __shfl_xor(x, 2, 64);
    x += __shfl_xor(x, 4, 64);
    x += __shfl_xor(x, 8, 64);
    if (p == 0) out[b] = 1.f / (1.f + __expf(-(x + bfc[0])));
}

extern "C" void kernel_launch(void* const* d_in, const int* in_sizes, int n_in,
                              void* d_out, int out_size, void* d_ws, size_t ws_size,
                              hipStream_t stream)
{
    const int* left_x      = (const int*)d_in[0];
    const int* right_x     = (const int*)d_in[2];
    const int* left_batch  = (const int*)d_in[4];
    const int* right_batch = (const int*)d_in[5];
    const int* anc_d  = (const int*)d_in[8];
    const int* leaf_d = (const int*)d_in[9];
    const int* anc_p  = (const int*)d_in[10];
    const int* leaf_p = (const int*)d_in[11];
    const int* anc_a  = (const int*)d_in[12];
    const int* leaf_a = (const int*)d_in[13];
    const float* emb_d = (const float*)d_in[14];
    const float* emb_p = (const float*)d_in[15];
    const float* emb_a = (const float*)d_in[16];
    const float* Wl_d = (const float*)d_in[17];
    const float* bl_d = (const float*)d_in[18];
    const float* ap_d = (const float*)d_in[19];
    const float* Wl_p = (const float*)d_in[20];
    const float* bl_p = (const float*)d_in[21];
    const float* ap_p = (const float*)d_in[22];
    const float* Wl_a = (const float*)d_in[23];
    const float* bl_a = (const float*)d_in[24];
    const float* ap_a = (const float*)d_in[25];
    const float* W_ntn = (const float*)d_in[26];
    const float* V_ntn = (const float*)d_in[27];
    const float* b_ntn = (const float*)d_in[28];
    const float* w_fc  = (const float*)d_in[29];
    const float* b_fc  = (const float*)d_in[30];
    float* out = (float*)d_out;

    float* ws = (float*)d_ws;
    float* s_sum   = ws;                                    // 64 floats (16 used)
    float* le      = ws + 64;                               // 4096*128
    float* re      = le + (size_t)BB * HID;                 // 4096*128
    float* all_emb = re + (size_t)BB * HID;                 // 18000*128
    float* part    = all_emb + (size_t)(VD + VP + VA) * HID;// 8*4096*16
    int*   segL    = (int*)(part + (size_t)8 * BB * PD);    // 4100
    int*   segR    = segL + 4100;                           // 4100
    bf16*  U       = (bf16*)(segR + 4100);                  // 23400*256 bf16
    bf16*  U_d = U;
    bf16*  U_p = U_d + (size_t)NGD * 256;
    bf16*  U_a = U_p + (size_t)NGP * 256;
    bf16*  B3_d = U_a + (size_t)NGA * 256;                  // 3 * 32768 bf16
    bf16*  B3_p = B3_d + 32768;
    bf16*  B3_a = B3_p + 32768;

    prep_b3<<<48, 256, 0, stream>>>(Wl_d, Wl_p, Wl_a, B3_d, B3_p, B3_a);

    seg_bounds<<<33, 256, 0, stream>>>(left_batch, right_batch, segL, segR, s_sum);

    stage1_mfma<<<NB_D + NB_P + NB_A, 256, 0, stream>>>(
        emb_d, B3_d, U_d, emb_p, B3_p, U_p, emb_a, B3_a, U_a);

    aw_all<<<1024, 256, 0, stream>>>(
        U_d, anc_d, leaf_d, bl_d, ap_d,
        U_p, anc_p, leaf_p, bl_p, ap_p,
        U_a, anc_a, leaf_a, bl_a, ap_a, s_sum);

    allemb_all<<<1024, 256, 0, stream>>>(
        emb_d, anc_d, emb_p, anc_p, emb_a, anc_a, s_sum, all_emb);

    segsum_f2<<<2 * BB, 256, 0, stream>>>(
        all_emb, left_x, segL, le, right_x, segR, re);

    ntn_part<<<dim3(64, 8), 256, 0, stream>>>(le, re, W_ntn, part);

    ntn_epi<<<BB / 16, 256, 0, stream>>>(part, le, re, V_ntn, b_ntn, w_fc, b_fc, out);
}

// Round 7
// 235.102 us; speedup vs baseline: 2.2738x; 1.0127x over previous
//
#include <hip/hip_runtime.h>
#include <hip/hip_bf16.h>

typedef __hip_bfloat16 bf16;
typedef __attribute__((ext_vector_type(8))) short bf16x8;
typedef __attribute__((ext_vector_type(4))) float f32x4;

#define HID 128
#define PD  16
#define BB  4096
#define TT  262144
#define VD  10000
#define VP  4000
#define VA  4000
#define NGD 13000
#define NGP 5200
#define NGA 5200

#define NB_D ((NGD + 31) / 32)   // 407
#define NB_P ((NGP + 31) / 32)   // 163
#define NB_A ((NGA + 31) / 32)   // 163

__device__ __forceinline__ float2 bf2x(unsigned int u) {
    float lo = __uint_as_float(u << 16);
    float hi = __uint_as_float(u & 0xffff0000u);
    return make_float2(lo, hi);
}

union Pack2 { bf16 h[2]; unsigned int u; };
__device__ __forceinline__ unsigned int pk2(float a, float b) {
    Pack2 p; p.h[0] = __float2bfloat16(a); p.h[1] = __float2bfloat16(b); return p.u;
}

// ---------------- K0: prep W fragments (fragment-major bf16 for MFMA A-operand)
__global__ __launch_bounds__(256) void prep_b3(
    const float* __restrict__ Wl_d, const float* __restrict__ Wl_p, const float* __restrict__ Wl_a,
    bf16* __restrict__ B3_d, bf16* __restrict__ B3_p, bf16* __restrict__ B3_a)
{
    const int sec = blockIdx.x >> 4, jt = blockIdx.x & 15;
    const float* Wl = (sec == 0) ? Wl_d : (sec == 1) ? Wl_p : Wl_a;
    bf16* B3 = (sec == 0) ? B3_d : (sec == 1) ? B3_p : B3_a;
    const int tid = threadIdx.x;
    const int q = tid >> 6, lane = tid & 63;
    const int quad = lane >> 4, m = lane & 15;
    const int col = jt * 16 + m;
    const float* src = (col < 128) ? (Wl + col * 256) : (Wl + (col - 128) * 256 + 128);
    unsigned int pk[4];
#pragma unroll
    for (int jp = 0; jp < 4; ++jp) {
        int k0 = q * 32 + quad * 8 + 2 * jp;
        pk[jp] = pk2(src[k0], src[k0 + 1]);
    }
    uint4 val = make_uint4(pk[0], pk[1], pk[2], pk[3]);
    *reinterpret_cast<uint4*>(B3 + ((size_t)(jt * 4 + q) * 64 + lane) * 8) = val;
}

// ---------------- K1: U[g, 0..255] via bf16 MFMA
__device__ __forceinline__ void stage1_body(
    unsigned short (*Abf)[136],
    const float* __restrict__ emb, const bf16* __restrict__ B3,
    bf16* __restrict__ U, int NG, int blk)
{
    const int tid  = threadIdx.x;
    const int row0 = blk * 32;
    {
        const int r = tid >> 3, seg = tid & 7;
        const int g = row0 + r;
        float v[16];
        if (g < NG) {
            const float4* src = reinterpret_cast<const float4*>(emb + (size_t)g * HID + seg * 16);
#pragma unroll
            for (int i = 0; i < 4; ++i) {
                float4 f = src[i];
                v[4 * i] = f.x; v[4 * i + 1] = f.y; v[4 * i + 2] = f.z; v[4 * i + 3] = f.w;
            }
        } else {
#pragma unroll
            for (int i = 0; i < 16; ++i) v[i] = 0.f;
        }
        unsigned int pk[8];
#pragma unroll
        for (int i = 0; i < 8; ++i) pk[i] = pk2(v[2 * i], v[2 * i + 1]);
        uint4* dst = reinterpret_cast<uint4*>(&Abf[r][seg * 16]);
        dst[0] = make_uint4(pk[0], pk[1], pk[2], pk[3]);
        dst[1] = make_uint4(pk[4], pk[5], pk[6], pk[7]);
    }
    __syncthreads();

    const int lane   = tid & 63;
    const int w      = tid >> 6;
    const int gtile  = w & 1;
    const int jstrip = w >> 1;
    const int lrow   = gtile * 16 + (lane & 15);
    const int koff   = (lane >> 4) * 8;
    const bf16x8* B3f = reinterpret_cast<const bf16x8*>(B3);

    f32x4 acc[8];
#pragma unroll
    for (int t = 0; t < 8; ++t) acc[t] = (f32x4){0.f, 0.f, 0.f, 0.f};

#pragma unroll
    for (int q = 0; q < 4; ++q) {
        bf16x8 ef = *reinterpret_cast<const bf16x8*>(&Abf[lrow][q * 32 + koff]);
#pragma unroll
        for (int t = 0; t < 8; ++t) {
            int jt = jstrip * 8 + t;
            bf16x8 wf = B3f[(jt * 4 + q) * 64 + lane];
            acc[t] = __builtin_amdgcn_mfma_f32_16x16x32_bf16(wf, ef, acc[t], 0, 0, 0);
        }
    }

    const int g = row0 + gtile * 16 + (lane & 15);
    if (g < NG) {
        const int quad = lane >> 4;
        bf16* Ur = U + (size_t)g * 256;
#pragma unroll
        for (int t = 0; t < 8; ++t) {
            int j0 = (jstrip * 8 + t) * 16 + quad * 4;
            uint2 st = make_uint2(pk2(acc[t].x, acc[t].y), pk2(acc[t].z, acc[t].w));
            *reinterpret_cast<uint2*>(Ur + j0) = st;
        }
    }
}

__global__ __launch_bounds__(256) void stage1_mfma(
    const float* __restrict__ emb_d, const bf16* __restrict__ B3_d, bf16* __restrict__ U_d,
    const float* __restrict__ emb_p, const bf16* __restrict__ B3_p, bf16* __restrict__ U_p,
    const float* __restrict__ emb_a, const bf16* __restrict__ B3_a, bf16* __restrict__ U_a)
{
    __shared__ unsigned short Abf[32][136];
    int bx = blockIdx.x;
    if (bx < NB_D)             stage1_body(Abf, emb_d, B3_d, U_d, NGD, bx);
    else if (bx < NB_D + NB_P) stage1_body(Abf, emb_p, B3_p, U_p, NGP, bx - NB_D);
    else                       stage1_body(Abf, emb_a, B3_a, U_a, NGA, bx - NB_D - NB_P);
}

// ---------------- K2: aw + softmax + global s_sum  (2 vertices per iteration)
template <int L>
__device__ __forceinline__ void aw_body(
    float* sacc,
    const bf16* __restrict__ U, const int* __restrict__ anc, const int* __restrict__ leaf,
    const float* __restrict__ bl, const float* __restrict__ ap,
    float* __restrict__ s_out, int V, int blk, int nblk)
{
    const int tid  = threadIdx.x;
    const int lane = tid & 63;
    const int wid  = blk * 4 + (tid >> 6);
    const int nw   = nblk * 4;
    const float2 blv = *reinterpret_cast<const float2*>(bl + 2 * lane);
    const float2 apv = *reinterpret_cast<const float2*>(ap + 2 * lane);
    const unsigned int* Uw = reinterpret_cast<const unsigned int*>(U);
    float wacc[L];
#pragma unroll
    for (int l = 0; l < L; ++l) wacc[l] = 0.f;

    for (int vp = wid; vp < V / 2; vp += nw) {
        const int v0 = 2 * vp;
        int a0[L], f0[L], a1[L], f1[L];
        if (L == 4) {
            int4 ia = *reinterpret_cast<const int4*>(anc  + (size_t)v0 * 4);
            int4 ib = *reinterpret_cast<const int4*>(anc  + (size_t)v0 * 4 + 4);
            int4 fa = *reinterpret_cast<const int4*>(leaf + (size_t)v0 * 4);
            int4 fb = *reinterpret_cast<const int4*>(leaf + (size_t)v0 * 4 + 4);
            a0[0] = ia.x; a0[1] = ia.y; a0[2] = ia.z; a0[3] = ia.w;
            a1[0] = ib.x; a1[1] = ib.y; a1[2] = ib.z; a1[3] = ib.w;
            f0[0] = fa.x; f0[1] = fa.y; f0[2] = fa.z; f0[3] = fa.w;
            f1[0] = fb.x; f1[1] = fb.y; f1[2] = fb.z; f1[3] = fb.w;
        } else {
#pragma unroll
            for (int l = 0; l < L; ++l) {
                a0[l] = anc[(size_t)v0 * L + l];
                a1[l] = anc[(size_t)(v0 + 1) * L + l];
                f0[l] = leaf[(size_t)v0 * L + l];
                f1[l] = leaf[(size_t)(v0 + 1) * L + l];
            }
        }
        unsigned int ua0[L], ul0[L], ua1[L], ul1[L];
#pragma unroll
        for (int l = 0; l < L; ++l) {
            ua0[l] = Uw[(size_t)a0[l] * 128 + lane];
            ul0[l] = Uw[(size_t)f0[l] * 128 + 64 + lane];
            ua1[l] = Uw[(size_t)a1[l] * 128 + lane];
            ul1[l] = Uw[(size_t)f1[l] * 128 + 64 + lane];
        }
        float aw0[L], aw1[L];
#pragma unroll
        for (int l = 0; l < L; ++l) {
            float2 x0 = bf2x(ua0[l]), y0 = bf2x(ul0[l]);
            float2 x1 = bf2x(ua1[l]), y1 = bf2x(ul1[l]);
            float p0 = tanhf(x0.x + y0.x + blv.x) * apv.x + tanhf(x0.y + y0.y + blv.y) * apv.y;
            float p1 = tanhf(x1.x + y1.x + blv.x) * apv.x + tanhf(x1.y + y1.y + blv.y) * apv.y;
#pragma unroll
            for (int off = 32; off; off >>= 1) {
                p0 += __shfl_xor(p0, off, 64);
                p1 += __shfl_xor(p1, off, 64);
            }
            aw0[l] = p0; aw1[l] = p1;
        }
        float m0 = aw0[0], m1 = aw1[0];
#pragma unroll
        for (int l = 1; l < L; ++l) { m0 = fmaxf(m0, aw0[l]); m1 = fmaxf(m1, aw1[l]); }
        float d0 = 0.f, d1 = 0.f, e0[L], e1[L];
#pragma unroll
        for (int l = 0; l < L; ++l) {
            e0[l] = __expf(aw0[l] - m0); d0 += e0[l];
            e1[l] = __expf(aw1[l] - m1); d1 += e1[l];
        }
        float i0 = 1.f / d0, i1 = 1.f / d1;
#pragma unroll
        for (int l = 0; l < L; ++l) wacc[l] += e0[l] * i0 + e1[l] * i1;
    }
    if (lane == 0) {
#pragma unroll
        for (int l = 0; l < L; ++l) atomicAdd(&sacc[l], wacc[l]);
    }
    __syncthreads();
    if (tid < L) atomicAdd(&s_out[tid], sacc[tid]);
}

__global__ __launch_bounds__(256) void aw_all(
    const bf16* __restrict__ U_d, const int* __restrict__ anc_d, const int* __restrict__ leaf_d,
    const float* __restrict__ bl_d, const float* __restrict__ ap_d,
    const bf16* __restrict__ U_p, const int* __restrict__ anc_p, const int* __restrict__ leaf_p,
    const float* __restrict__ bl_p, const float* __restrict__ ap_p,
    const bf16* __restrict__ U_a, const int* __restrict__ anc_a, const int* __restrict__ leaf_a,
    const float* __restrict__ bl_a, const float* __restrict__ ap_a,
    float* __restrict__ s_sum)
{
    __shared__ float sacc[5];
    const int tid = threadIdx.x;
    if (tid < 5) sacc[tid] = 0.f;
    __syncthreads();
    int bx = blockIdx.x;
    if (bx < 512)      aw_body<4>(sacc, U_d, anc_d, leaf_d, bl_d, ap_d, s_sum + 0, VD, bx, 512);
    else if (bx < 768) aw_body<4>(sacc, U_p, anc_p, leaf_p, bl_p, ap_p, s_sum + 4, VP, bx - 512, 256);
    else               aw_body<5>(sacc, U_a, anc_a, leaf_a, bl_a, ap_a, s_sum + 8, VA, bx - 768, 256);
}

// ---------------- K3: all_emb (float4 gathers, 2 vertices per iteration)
template <int L>
__device__ __forceinline__ void allemb_body(
    const float* __restrict__ emb, const int* __restrict__ anc,
    const float* __restrict__ s, float* __restrict__ out, int V, int blk, int nblk)
{
    const int tid   = threadIdx.x;
    const int lane4 = tid & 31;
    const int vslot = tid >> 5;
    const float4* emb4 = reinterpret_cast<const float4*>(emb);
    float4* out4 = reinterpret_cast<float4*>(out);
    float sv[L];
#pragma unroll
    for (int l = 0; l < L; ++l) sv[l] = s[l];
    for (int vp = blk * 8 + vslot; vp < V / 2; vp += nblk * 8) {
        const int v0 = 2 * vp;
        int a0[L], a1[L];
        if (L == 4) {
            int4 ia = *reinterpret_cast<const int4*>(anc + (size_t)v0 * 4);
            int4 ib = *reinterpret_cast<const int4*>(anc + (size_t)v0 * 4 + 4);
            a0[0] = ia.x; a0[1] = ia.y; a0[2] = ia.z; a0[3] = ia.w;
            a1[0] = ib.x; a1[1] = ib.y; a1[2] = ib.z; a1[3] = ib.w;
        } else {
#pragma unroll
            for (int l = 0; l < L; ++l) {
                a0[l] = anc[(size_t)v0 * L + l];
                a1[l] = anc[(size_t)(v0 + 1) * L + l];
            }
        }
        float4 e0[L], e1[L];
#pragma unroll
        for (int l = 0; l < L; ++l) {
            e0[l] = emb4[(size_t)a0[l] * 32 + lane4];
            e1[l] = emb4[(size_t)a1[l] * 32 + lane4];
        }
        float4 r0 = make_float4(0.f, 0.f, 0.f, 0.f);
        float4 r1 = make_float4(0.f, 0.f, 0.f, 0.f);
#pragma unroll
        for (int l = 0; l < L; ++l) {
            r0.x += sv[l] * e0[l].x; r0.y += sv[l] * e0[l].y;
            r0.z += sv[l] * e0[l].z; r0.w += sv[l] * e0[l].w;
            r1.x += sv[l] * e1[l].x; r1.y += sv[l] * e1[l].y;
            r1.z += sv[l] * e1[l].z; r1.w += sv[l] * e1[l].w;
        }
        out4[(size_t)v0 * 32 + lane4]       = r0;
        out4[(size_t)(v0 + 1) * 32 + lane4] = r1;
    }
}

__global__ __launch_bounds__(256) void allemb_all(
    const float* __restrict__ emb_d, const int* __restrict__ anc_d,
    const float* __restrict__ emb_p, const int* __restrict__ anc_p,
    const float* __restrict__ emb_a, const int* __restrict__ anc_a,
    const float* __restrict__ s_sum, float* __restrict__ all_emb)
{
    int bx = blockIdx.x;
    if (bx < 512)
        allemb_body<4>(emb_d, anc_d, s_sum + 0, all_emb, VD, bx, 512);
    else if (bx < 768)
        allemb_body<4>(emb_p, anc_p, s_sum + 4, all_emb + (size_t)VD * HID, VP, bx - 512, 256);
    else
        allemb_body<5>(emb_a, anc_a, s_sum + 8, all_emb + (size_t)(VD + VP) * HID, VA, bx - 768, 256);
}

// ---------------- K4a: segment bounds + zero s_sum (fused)
__global__ __launch_bounds__(256) void seg_bounds(
    const int* __restrict__ lb, const int* __restrict__ rb,
    int* __restrict__ segL, int* __restrict__ segR, float* __restrict__ s_sum)
{
    int gid = blockIdx.x * 256 + threadIdx.x;
    if (gid >= 2 * BB + 8 && gid < 2 * BB + 24) s_sum[gid - (2 * BB + 8)] = 0.f;
    const int* batch;
    int* segp;
    int b;
    if (gid <= BB) { batch = lb; segp = segL; b = gid; }
    else if (gid <= 2 * BB + 1) { batch = rb; segp = segR; b = gid - BB - 1; }
    else return;
    int l = 0, r = TT;
    while (l < r) { int m = (l + r) >> 1; if (batch[m] < b) l = m + 1; else r = m; }
    segp[b] = l;
}

// ---------------- K4b: segment sum — max-MLP: f4 half-wave slots, 2 rows/instr,
// 16 rows (8KB) in flight per wave, coalesced index preload + shfl distribute.
__global__ __launch_bounds__(256) void segsum_mlp(
    const float* __restrict__ all_emb,
    const int* __restrict__ lx, const int* __restrict__ segL, float* __restrict__ le,
    const int* __restrict__ rx, const int* __restrict__ segR, float* __restrict__ re)
{
    __shared__ float4 red[4][32];
    const int tid  = threadIdx.x;
    const int b    = blockIdx.x & (BB - 1);
    const int lane = tid & 63;
    const int w    = tid >> 6;
    const int* x;
    const int* seg;
    float* out;
    if (blockIdx.x < BB) { x = lx; seg = segL; out = le; }
    else                 { x = rx; seg = segR; out = re; }
    const int lo = seg[b], hi = seg[b + 1];
    const int half  = lane >> 5;    // 0 or 1
    const int lane4 = lane & 31;
    const float4* AE4 = reinterpret_cast<const float4*>(all_emb);
    float4 acc = make_float4(0.f, 0.f, 0.f, 0.f);

    for (int tb = lo + 16 * w; tb < hi; tb += 64) {
        // coalesced: 16 consecutive indices for this wave's 16 rows
        int idxv = x[min(tb + (lane & 15), hi - 1)];
        float4 v[8];
        int val[8];
#pragma unroll
        for (int u = 0; u < 8; ++u) {
            int src = 2 * u + half;               // row within the 16
            int ridx = __shfl(idxv, src, 64);
            val[u] = (tb + src) < hi;
            v[u] = AE4[(size_t)ridx * 32 + lane4];
        }
#pragma unroll
        for (int u = 0; u < 8; ++u) {
            if (val[u]) {
                acc.x += v[u].x; acc.y += v[u].y;
                acc.z += v[u].z; acc.w += v[u].w;
            }
        }
    }
    // sum the two half-wave slots (different rows, same columns)
    acc.x += __shfl_xor(acc.x, 32, 64);
    acc.y += __shfl_xor(acc.y, 32, 64);
    acc.z += __shfl_xor(acc.z, 32, 64);
    acc.w += __shfl_xor(acc.w, 32, 64);
    if (lane < 32) red[w][lane4] = acc;
    __syncthreads();
    if (tid < 32) {
        float4 r0 = red[0][tid], r1 = red[1][tid], r2 = red[2][tid], r3 = red[3][tid];
        float4 s;
        s.x = r0.x + r1.x + r2.x + r3.x;
        s.y = r0.y + r1.y + r2.y + r3.y;
        s.z = r0.z + r1.z + r2.z + r3.z;
        s.w = r0.w + r1.w + r2.w + r3.w;
        reinterpret_cast<float4*>(out)[(size_t)b * 32 + tid] = s;
    }
}

// ---------------- K5a: NTN GEMM tile + contraction with re -> partial bilinear
__global__ __launch_bounds__(256) void ntn_part(
    const float* __restrict__ le, const float* __restrict__ re,
    const float* __restrict__ W2, float* __restrict__ part)
{
    __shared__ float Alds[32][68];
    __shared__ float Blds[32 * 264];
    __shared__ float Rlds[64][17];
    const int tid   = threadIdx.x;
    const int row0  = blockIdx.x * 64;
    const int col0  = blockIdx.y * 256;
    const int lane5 = tid & 31;
    const int rbase = (tid >> 5) * 8;
    const int cbase = lane5 * 8;
    float acc[8][8];
#pragma unroll
    for (int i = 0; i < 8; ++i)
#pragma unroll
        for (int j = 0; j < 8; ++j) acc[i][j] = 0.f;

    for (int i = tid; i < 64 * 16; i += 256) {
        int rr = i >> 4, jl = i & 15;
        Rlds[rr][jl] = re[(size_t)(row0 + rr) * HID + blockIdx.y * 16 + jl];
    }

    for (int k0 = 0; k0 < 128; k0 += 32) {
        __syncthreads();
        for (int i = tid; i < 64 * 32; i += 256) {
            int rr = i >> 5, kk = i & 31;
            Alds[kk][rr] = le[(size_t)(row0 + rr) * HID + k0 + kk];
        }
        for (int i = tid; i < 32 * 64; i += 256) {
            int kk = i >> 6, j4 = (i & 63) * 4;
            float4 v = *reinterpret_cast<const float4*>(&W2[(size_t)(k0 + kk) * 2048 + col0 + j4]);
            *reinterpret_cast<float4*>(&Blds[kk * 264 + j4]) = v;
        }
        __syncthreads();
#pragma unroll
        for (int kk = 0; kk < 32; ++kk) {
            float4 a0 = *reinterpret_cast<const float4*>(&Alds[kk][rbase]);
            float4 a1 = *reinterpret_cast<const float4*>(&Alds[kk][rbase + 4]);
            float4 b0 = *reinterpret_cast<const float4*>(&Blds[kk * 264 + cbase]);
            float4 b1 = *reinterpret_cast<const float4*>(&Blds[kk * 264 + cbase + 4]);
            float av[8] = {a0.x, a0.y, a0.z, a0.w, a1.x, a1.y, a1.z, a1.w};
            float bv[8] = {b0.x, b0.y, b0.z, b0.w, b1.x, b1.y, b1.z, b1.w};
#pragma unroll
            for (int i = 0; i < 8; ++i)
#pragma unroll
                for (int j = 0; j < 8; ++j) acc[i][j] += av[i] * bv[j];
        }
    }

    const int jloc = lane5 >> 1;
    const int pq   = (tid & 1) * 8;
#pragma unroll
    for (int i = 0; i < 8; ++i) {
        int row = rbase + i;
        float rj = Rlds[row][jloc];
        float pb[8];
#pragma unroll
        for (int j = 0; j < 8; ++j) pb[j] = acc[i][j] * rj;
#pragma unroll
        for (int m = 2; m <= 16; m <<= 1) {
#pragma unroll
            for (int j = 0; j < 8; ++j) pb[j] += __shfl_xor(pb[j], m, 64);
        }
        if ((tid & 30) == 0) {
            size_t base = ((size_t)blockIdx.y * BB + row0 + row) * PD + pq;
            *reinterpret_cast<float4*>(&part[base])     = make_float4(pb[0], pb[1], pb[2], pb[3]);
            *reinterpret_cast<float4*>(&part[base + 4]) = make_float4(pb[4], pb[5], pb[6], pb[7]);
        }
    }
}

// ---------------- K5b: sum partials + block term + tanh + fc + sigmoid
__global__ __launch_bounds__(256) void ntn_epi(
    const float* __restrict__ part, const float* __restrict__ le, const float* __restrict__ re,
    const float* __restrict__ Vntn, const float* __restrict__ bntn,
    const float* __restrict__ wfc, const float* __restrict__ bfc,
    float* __restrict__ out)
{
    __shared__ float Vlds[16 * 257];
    __shared__ float LE[16 * 128];
    __shared__ float RE[16 * 128];
    const int tid = threadIdx.x;
    const int b0  = blockIdx.x * 16;
    for (int i = tid; i < 4096; i += 256) Vlds[(i >> 8) * 257 + (i & 255)] = Vntn[i];
    for (int i = tid; i < 2048; i += 256) {
        LE[i] = le[(size_t)b0 * HID + i];
        RE[i] = re[(size_t)b0 * HID + i];
    }
    __syncthreads();
    const int bl = tid >> 4, p = tid & 15;
    const int b  = b0 + bl;
    float bil = 0.f;
#pragma unroll
    for (int by = 0; by < 8; ++by) bil += part[((size_t)by * BB + b) * PD + p];
    float s = bil + bntn[p];
    const float* Vp   = &Vlds[p * 257];
    const float* lrow = &LE[bl * 128];
    const float* rrow = &RE[bl * 128];
#pragma unroll 8
    for (int c = 0; c < 128; ++c) s += lrow[c] * Vp[c] + rrow[c] * Vp[128 + c];
    float x = tanhf(s) * wfc[p];
    x += __shfl_xor(x, 1, 64);
    x += __shfl_xor(x, 2, 64);
    x += __shfl_xor(x, 4, 64);
    x += __shfl_xor(x, 8, 64);
    if (p == 0) out[b] = 1.f / (1.f + __expf(-(x + bfc[0])));
}

extern "C" void kernel_launch(void* const* d_in, const int* in_sizes, int n_in,
                              void* d_out, int out_size, void* d_ws, size_t ws_size,
                              hipStream_t stream)
{
    const int* left_x      = (const int*)d_in[0];
    const int* right_x     = (const int*)d_in[2];
    const int* left_batch  = (const int*)d_in[4];
    const int* right_batch = (const int*)d_in[5];
    const int* anc_d  = (const int*)d_in[8];
    const int* leaf_d = (const int*)d_in[9];
    const int* anc_p  = (const int*)d_in[10];
    const int* leaf_p = (const int*)d_in[11];
    const int* anc_a  = (const int*)d_in[12];
    const int* leaf_a = (const int*)d_in[13];
    const float* emb_d = (const float*)d_in[14];
    const float* emb_p = (const float*)d_in[15];
    const float* emb_a = (const float*)d_in[16];
    const float* Wl_d = (const float*)d_in[17];
    const float* bl_d = (const float*)d_in[18];
    const float* ap_d = (const float*)d_in[19];
    const float* Wl_p = (const float*)d_in[20];
    const float* bl_p = (const float*)d_in[21];
    const float* ap_p = (const float*)d_in[22];
    const float* Wl_a = (const float*)d_in[23];
    const float* bl_a = (const float*)d_in[24];
    const float* ap_a = (const float*)d_in[25];
    const float* W_ntn = (const float*)d_in[26];
    const float* V_ntn = (const float*)d_in[27];
    const float* b_ntn = (const float*)d_in[28];
    const float* w_fc  = (const float*)d_in[29];
    const float* b_fc  = (const float*)d_in[30];
    float* out = (float*)d_out;

    float* ws = (float*)d_ws;
    float* s_sum   = ws;                                    // 64 floats (16 used)
    float* le      = ws + 64;                               // 4096*128
    float* re      = le + (size_t)BB * HID;                 // 4096*128
    float* all_emb = re + (size_t)BB * HID;                 // 18000*128
    float* part    = all_emb + (size_t)(VD + VP + VA) * HID;// 8*4096*16
    int*   segL    = (int*)(part + (size_t)8 * BB * PD);    // 4100
    int*   segR    = segL + 4100;                           // 4100
    bf16*  U       = (bf16*)(segR + 4100);                  // 23400*256 bf16
    bf16*  U_d = U;
    bf16*  U_p = U_d + (size_t)NGD * 256;
    bf16*  U_a = U_p + (size_t)NGP * 256;
    bf16*  B3_d = U_a + (size_t)NGA * 256;                  // 3 * 32768 bf16
    bf16*  B3_p = B3_d + 32768;
    bf16*  B3_a = B3_p + 32768;

    prep_b3<<<48, 256, 0, stream>>>(Wl_d, Wl_p, Wl_a, B3_d, B3_p, B3_a);

    seg_bounds<<<33, 256, 0, stream>>>(left_batch, right_batch, segL, segR, s_sum);

    stage1_mfma<<<NB_D + NB_P + NB_A, 256, 0, stream>>>(
        emb_d, B3_d, U_d, emb_p, B3_p, U_p, emb_a, B3_a, U_a);

    aw_all<<<1024, 256, 0, stream>>>(
        U_d, anc_d, leaf_d, bl_d, ap_d,
        U_p, anc_p, leaf_p, bl_p, ap_p,
        U_a, anc_a, leaf_a, bl_a, ap_a, s_sum);

    allemb_all<<<1024, 256, 0, stream>>>(
        emb_d, anc_d, emb_p, anc_p, emb_a, anc_a, s_sum, all_emb);

    segsum_mlp<<<2 * BB, 256, 0, stream>>>(
        all_emb, left_x, segL, le, right_x, segR, re);

    ntn_part<<<dim3(64, 8), 256, 0, stream>>>(le, re, W_ntn, part);

    ntn_epi<<<BB / 16, 256, 0, stream>>>(part, le, re, V_ntn, b_ntn, w_fc, b_fc, out);
}